// Round 4
// baseline (1120.730 us; speedup 1.0000x reference)
//
#include <hip/hip_runtime.h>

namespace {

constexpr int NFFT  = 65536;   // complex FFT length (half of 131072)
constexpr int OUTW  = 65409;   // W - K + 1
// Y2[k1][m][f][c] : weight rfft spectrum, column-major for the fused MAC
constexpr size_t Y2BYTES = (size_t)256 * 129 * 128 * 8;

typedef float2 cplx;

__device__ __forceinline__ cplx cmk(float x, float y){ return make_float2(x, y); }
__device__ __forceinline__ cplx cadd(cplx a, cplx b){ return cmk(a.x+b.x, a.y+b.y); }
__device__ __forceinline__ cplx csub(cplx a, cplx b){ return cmk(a.x-b.x, a.y-b.y); }
__device__ __forceinline__ cplx cmul(cplx a, cplx b){ return cmk(a.x*b.x - a.y*b.y, a.x*b.y + a.y*b.x); }
__device__ __forceinline__ cplx cmulj(cplx a, cplx b){ // a * conj(b)
  return cmk(a.x*b.x + a.y*b.y, a.y*b.x - a.x*b.y); }

// 16-point complex DFT, natural order in/out. DIR=-1 forward, +1 inverse (unnormalized).
template<int DIR>
__device__ __forceinline__ void dft16(cplx v[16]) {
  const float C1 = 0.92387953251128674f;
  const float S1 = 0.38268343236508977f;
  const float C2 = 0.70710678118654752f;
  const float WR[16]  = {1.f, C1, C2, S1, 0.f, -S1, -C2, -C1, -1.f, -C1, -C2, -S1, 0.f, S1, C2, C1};
  const float WIF[16] = {0.f, -S1, -C2, -C1, -1.f, -C1, -C2, -S1, 0.f, S1, C2, C1, 1.f, C1, C2, S1};
  cplx s[16];
  #pragma unroll
  for (int n2 = 0; n2 < 4; ++n2) {
    cplx a = v[n2], b = v[n2+4], c = v[n2+8], d = v[n2+12];
    cplx ac = cadd(a,c), am = csub(a,c), bd = cadd(b,d), bm = csub(b,d);
    cplx x0 = cadd(ac, bd), x2 = csub(ac, bd), x1, x3;
    if (DIR == -1) { x1 = cmk(am.x + bm.y, am.y - bm.x); x3 = cmk(am.x - bm.y, am.y + bm.x); }
    else           { x1 = cmk(am.x - bm.y, am.y + bm.x); x3 = cmk(am.x + bm.y, am.y - bm.x); }
    s[0*4+n2] = x0;
    {
      int e1 = (n2*1) & 15, e2 = (n2*2) & 15, e3 = (n2*3) & 15;
      cplx w1 = cmk(WR[e1], (DIR==-1)? WIF[e1] : -WIF[e1]);
      cplx w2 = cmk(WR[e2], (DIR==-1)? WIF[e2] : -WIF[e2]);
      cplx w3 = cmk(WR[e3], (DIR==-1)? WIF[e3] : -WIF[e3]);
      s[1*4+n2] = cmul(x1, w1);
      s[2*4+n2] = cmul(x2, w2);
      s[3*4+n2] = cmul(x3, w3);
    }
  }
  #pragma unroll
  for (int t1 = 0; t1 < 4; ++t1) {
    cplx a = s[t1*4+0], b = s[t1*4+1], c = s[t1*4+2], d = s[t1*4+3];
    cplx ac = cadd(a,c), am = csub(a,c), bd = cadd(b,d), bm = csub(b,d);
    cplx x0 = cadd(ac,bd), x2 = csub(ac,bd), x1, x3;
    if (DIR == -1) { x1 = cmk(am.x + bm.y, am.y - bm.x); x3 = cmk(am.x - bm.y, am.y + bm.x); }
    else           { x1 = cmk(am.x - bm.y, am.y + bm.x); x3 = cmk(am.x + bm.y, am.y - bm.x); }
    v[t1+0] = x0; v[t1+4] = x1; v[t1+8] = x2; v[t1+12] = x3;
  }
}

// Four-step pass A (forward): inner 256-pt DFTs + big twiddle.
// k1-major output staged through padded LDS so global stores are contiguous.
template<int DIR>
__global__ __launch_bounds__(256)
void fft_pass_a(const cplx* __restrict__ in, long inStride, int inLen,
                cplx* __restrict__ T) {
  int blk = blockIdx.x;
  int seq = blk >> 4;
  int B0  = (blk & 15) << 4;
  int t = threadIdx.x;
  __shared__ cplx sm[4608];                    // 36864 B: union of two views
  cplx (*tile)[260] = (cplx(*)[260])sm;        // phase-1 view [16][260]
  cplx* tile2 = sm;                            // phase-2 view [256][18]
  {
    const cplx* src = in + (long)seq * inStride;
    int cb = t & 15, rg = t >> 4;
    #pragma unroll
    for (int i = 0; i < 16; ++i) {
      int a = i*16 + rg;
      int sIdx = a*256 + B0 + cb;
      cplx v = (sIdx < inLen) ? src[sIdx] : cmk(0.f, 0.f);
      tile[cb][a] = v;
    }
  }
  __syncthreads();
  int cc = t >> 4, j = t & 15;
  cplx x[16];
  #pragma unroll
  for (int a1 = 0; a1 < 16; ++a1) x[a1] = tile[cc][a1*16 + j];
  dft16<DIR>(x);
  {
    float sn, cs;
    __sincosf((float)DIR * 6.28318530717958648f * (float)j * (1.0f/256.0f), &sn, &cs);
    cplx r = cmk(cs, sn), cur = r;
    #pragma unroll
    for (int t1 = 1; t1 < 16; ++t1) { x[t1] = cmul(x[t1], cur); cur = cmul(cur, r); }
  }
  __syncthreads();
  #pragma unroll
  for (int t1 = 0; t1 < 16; ++t1) tile[cc][t1*16 + ((j + t1) & 15)] = x[t1];
  __syncthreads();
  #pragma unroll
  for (int a2 = 0; a2 < 16; ++a2) x[a2] = tile[cc][j*16 + ((a2 + j) & 15)];
  dft16<DIR>(x);
  int b = B0 + cc;
  __syncthreads();   // tile reads done; reuse as tile2
  {
    float sn, cs;
    __sincosf((float)DIR * 6.28318530717958648f * (float)(b*j) * (1.0f/65536.0f), &sn, &cs);
    cplx cur = cmk(cs, sn);
    __sincosf((float)DIR * 6.28318530717958648f * (float)b * (1.0f/4096.0f), &sn, &cs);
    cplx stp = cmk(cs, sn);
    #pragma unroll
    for (int t2 = 0; t2 < 16; ++t2) {
      tile2[(j + 16*t2)*18 + cc] = cmul(x[t2], cur);
      cur = cmul(cur, stp);
    }
  }
  __syncthreads();
  {
    int rg = t >> 4, cb = t & 15;
    cplx* dst = T + (long)seq * NFFT + B0 + cb;
    #pragma unroll
    for (int i = 0; i < 16; ++i) {
      int k1 = i*16 + rg;
      dst[(long)k1 * 256] = tile2[k1*18 + cb];
    }
  }
}

// Four-step pass B: outer 256-pt DFTs. MODE 1 = inverse-final with bias+trunc.
template<int DIR, int MODE>
__global__ __launch_bounds__(256)
void fft_pass_b(const cplx* __restrict__ T, cplx* __restrict__ outZ,
                float* __restrict__ outR, const float* __restrict__ bias,
                int seqBase) {
  int blk = blockIdx.x;
  int seq = blk >> 4;
  int K0  = (blk & 15) << 4;
  int t = threadIdx.x;
  __shared__ cplx tile[16][260];
  {
    const cplx* src = T + (long)seq * NFFT;
    int ck = t & 15, rg = t >> 4;
    #pragma unroll
    for (int i = 0; i < 16; ++i) {
      int b = i*16 + rg;
      tile[ck][b] = src[b*256 + K0 + ck];
    }
  }
  __syncthreads();
  int cc = t >> 4, j = t & 15;
  cplx x[16];
  #pragma unroll
  for (int a1 = 0; a1 < 16; ++a1) x[a1] = tile[cc][a1*16 + j];
  dft16<DIR>(x);
  {
    float sn, cs;
    __sincosf((float)DIR * 6.28318530717958648f * (float)j * (1.0f/256.0f), &sn, &cs);
    cplx r = cmk(cs, sn), cur = r;
    #pragma unroll
    for (int t1 = 1; t1 < 16; ++t1) { x[t1] = cmul(x[t1], cur); cur = cmul(cur, r); }
  }
  __syncthreads();
  #pragma unroll
  for (int t1 = 0; t1 < 16; ++t1) tile[cc][t1*16 + ((j + t1) & 15)] = x[t1];
  __syncthreads();
  #pragma unroll
  for (int a2 = 0; a2 < 16; ++a2) x[a2] = tile[cc][j*16 + ((a2 + j) & 15)];
  dft16<DIR>(x);
  __syncthreads();
  #pragma unroll
  for (int t2 = 0; t2 < 16; ++t2) tile[cc][j + 16*t2] = x[t2];
  __syncthreads();
  int ck2 = t & 15, rg2 = t >> 4;
  if (MODE == 0) {
    cplx* dst = outZ + (long)seq * NFFT + K0 + ck2;
    #pragma unroll
    for (int i = 0; i < 16; ++i) {
      int k2 = i*16 + rg2;
      dst[256*k2] = tile[ck2][k2];
    }
  } else {
    const float sc = 1.0f / 65536.0f;
    int gseq = seqBase + seq;
    float bf = bias[gseq & 15];
    float* dst = outR + (long)gseq * OUTW;
    #pragma unroll
    for (int i = 0; i < 16; ++i) {
      int k2 = i*16 + rg2;
      int s  = K0 + ck2 + 256*k2;
      int tp = 2*s;
      cplx v = tile[ck2][k2];
      if (tp < OUTW)     dst[tp]   = v.x * sc + bf;
      if (tp + 1 < OUTW) dst[tp+1] = v.y * sc + bf;
    }
  }
}

// Direct weight rfft into transposed layout Y2[k1][m][f][c], k = k1 + 256*m.
__global__ __launch_bounds__(256)
void weight_spec(const float* __restrict__ wgt, cplx* __restrict__ Y2) {
  const int k1 = blockIdx.x;      // 0..255
  const int fg = blockIdx.y;      // 0..7
  const int t  = threadIdx.x;
  __shared__ float wt[16][129];
  for (int e = t; e < 16*128; e += 256)
    wt[e >> 7][e & 127] = wgt[(fg*16 + (e >> 7))*128 + (e & 127)];
  __syncthreads();
  const int fcL = t & 15;
  const int fc  = fg*16 + fcL;
  for (int m = t >> 4; m < 129; m += 16) {
    int k = k1 + 256*m;
    if (k > 32768) break;
    float sn, cs;
    __sincosf(-3.14159265358979324f * (float)k * (1.0f/65536.0f), &sn, &cs);
    cplx r  = cmk(cs, sn);
    cplx r2 = cmul(r, r);
    cplx r4 = cmul(r2, r2);
    cplx r8 = cmul(r4, r4);
    cplx av[8];
    #pragma unroll
    for (int v = 0; v < 8; ++v) av[v] = cmk(0.f, 0.f);
    cplx C = cmk(1.f, 0.f);
    #pragma unroll
    for (int u = 0; u < 16; ++u) {
      #pragma unroll
      for (int v = 0; v < 8; ++v) {
        float w = wt[fcL][u*8 + v];
        av[v].x += w * C.x;
        av[v].y += w * C.y;
      }
      C = cmul(C, r8);
    }
    cplx acc = av[7];
    #pragma unroll
    for (int v = 6; v >= 0; --v) acc = cadd(av[v], cmul(r, acc));
    Y2[((long)k1*129 + m)*128 + fc] = acc;
  }
}

// Fused middle stage v4.
//  - Xs merged into the Ts LDS region (mirror Z staged to registers first):
//    LDS 50176 -> 33280 B => 4 blocks/CU.
//  - __launch_bounds__(256,4): VGPR 132 was just over the 128 occupancy
//    cliff (waves/SIMD halve at 64/128/256); cap to 128.
//  - XCD-aware remap (remap=1, Bn=16): XCD = dispatch%8 = blockIdx.x; each
//    XCD runs 16 consecutive same-p blocks so the 264-KB Y2 column pair is
//    reused 16x out of its private 4-MB L2 instead of re-fetched by 8 XCDs.
__global__ __launch_bounds__(256, 4)
void fused_mid(const cplx* __restrict__ T1, const cplx* __restrict__ Y2,
               cplx* __restrict__ T2, int remap) {
  int p, ln;
  if (remap) {
    int xcd = blockIdx.x;              // 0..7 (= dispatch index % 8)
    int y   = blockIdx.y;              // 0..257
    if (y < 256) { p = xcd + 8*(y >> 4); ln = y & 15; }
    else         { p = 128;            ln = ((y - 256) << 3) | xcd; }
  } else {
    ln = blockIdx.x;
    p  = blockIdx.y;
  }
  const int cLo = p;
  const int cHi = (256 - p) & 255;
  const bool selfp = (p == 0) || (p == 128);
  const int t = threadIdx.x;
  const int g = t >> 4;                // 16 groups of 16 lanes (wave-aligned)
  const int j = t & 15;
  const int c = g & 7;
  const int half = g >> 3;
  const int col = half ? cHi : cLo;

  __shared__ cplx sm[16*260];          // 33280 B, two views:
  cplx (*Ts)[260]      = (cplx(*)[260])sm;       // transpose / Z-exchange
  cplx (*Xv)[2][130]   = (cplx(*)[2][130])sm;    // X view = Ts rows 0..7

  const float C16 = 0.98078528040323044913f;  // cos(pi/16)
  const float S16 = 0.19509032201612826785f;  // sin(pi/16)

  // ---- Phase F: forward DFT-256 over b, one column per group-half ----
  cplx x[16];
  {
    const cplx* src = T1 + ((long)(ln*8 + c) * NFFT + (long)col * 256);
    #pragma unroll
    for (int a1 = 0; a1 < 16; ++a1) x[a1] = src[a1*16 + j];
  }
  dft16<-1>(x);
  {
    float sn, cs;
    __sincosf(-6.28318530717958648f * (float)j * (1.0f/256.0f), &sn, &cs);
    cplx r = cmk(cs, sn), cur = r;
    #pragma unroll
    for (int t1 = 1; t1 < 16; ++t1) { x[t1] = cmul(x[t1], cur); cur = cmul(cur, r); }
  }
  #pragma unroll
  for (int t1 = 0; t1 < 16; ++t1) Ts[g][t1*16 + ((j + t1) & 15)] = x[t1];
  #pragma unroll
  for (int a2 = 0; a2 < 16; ++a2) x[a2] = Ts[g][j*16 + ((a2 + j) & 15)];
  dft16<-1>(x);
  #pragma unroll
  for (int t2 = 0; t2 < 16; ++t2) Ts[g][j + 16*t2] = x[t2];
  __syncthreads();

  // ---- stage mirror Z to registers, then overwrite Ts rows 0..7 with X ----
  cplx zmr[8];
  #pragma unroll
  for (int t2 = 0; t2 < 8; ++t2) {
    int m = j + 16*t2;
    int k = col + 256*m;
    int mi = (65536 - k) & 65535;
    zmr[t2] = Ts[g ^ 8][mi >> 8];
  }
  __syncthreads();                     // all Z reads done; Ts rows 0..7 free
  {
    float sn, cs;
    __sincosf(-3.14159265358979324f * (float)(col + 256*j) * (1.0f/65536.0f), &sn, &cs);
    cplx w = cmk(cs, sn);
    const cplx stp = cmk(C16, -S16);
    #pragma unroll
    for (int t2 = 0; t2 < 8; ++t2) {
      int m = j + 16*t2;
      cplx zk = x[t2];
      cplx zm = zmr[t2];
      cplx E = cmk(0.5f*(zk.x + zm.x), 0.5f*(zk.y - zm.y));
      cplx D = cmk(zk.x - zm.x, zk.y + zm.y);
      cplx O = cmk(0.5f*D.y, -0.5f*D.x);
      Xv[c][half][m] = cadd(E, cmul(w, O));
      w = cmul(w, stp);
    }
  }
  if (p == 0 && half == 0 && j == 0) {
    cplx zk = x[8];
    cplx X = cmk(zk.x, -zk.y);
    Xv[c][0][128] = X;
    Xv[c][1][128] = X;
  }
  __syncthreads();

  // ---- Phase M: one MAC per bin, pack twice, shfl the mirror half ----
  const int f = g;
  cplx zA[16], zB[16];

#define MAC_PASS(Q, XSEL, ZD, ZM, SRCLANE)                                     \
  do {                                                                         \
    const int q_ = (Q);                                                        \
    float sn_, cs_;                                                            \
    __sincosf(3.14159265358979324f * (float)(q_ + 256*j) * (1.0f/65536.0f),    \
              &sn_, &cs_);                                                     \
    cplx wp = cmk(cs_, sn_);                                                   \
    const cplx stp = cmk(C16, S16);                                            \
    const float4* yb = reinterpret_cast<const float4*>(                        \
        Y2 + ((long)q_*129 + j)*128 + f*8);                                    \
    float4 b0 = yb[0], b1 = yb[1], b2 = yb[2], b3 = yb[3];                     \
    _Pragma("unroll")                                                          \
    for (int t2 = 0; t2 < 8; ++t2) {                                           \
      float4 y0 = b0, y1 = b1, y2 = b2, y3 = b3;                               \
      if (t2 < 7) {                                                            \
        const float4* nx = yb + (long)(t2+1)*1024;                             \
        b0 = nx[0]; b1 = nx[1]; b2 = nx[2]; b3 = nx[3];                        \
      }                                                                        \
      int m = j + 16*t2;                                                       \
      cplx S = cmulj(Xv[0][XSEL][m], cmk(y0.x, y0.y));                         \
      S = cadd(S, cmulj(Xv[1][XSEL][m], cmk(y0.z, y0.w)));                     \
      S = cadd(S, cmulj(Xv[2][XSEL][m], cmk(y1.x, y1.y)));                     \
      S = cadd(S, cmulj(Xv[3][XSEL][m], cmk(y1.z, y1.w)));                     \
      S = cadd(S, cmulj(Xv[4][XSEL][m], cmk(y2.x, y2.y)));                     \
      S = cadd(S, cmulj(Xv[5][XSEL][m], cmk(y2.z, y2.w)));                     \
      S = cadd(S, cmulj(Xv[6][XSEL][m], cmk(y3.x, y3.y)));                     \
      S = cadd(S, cmulj(Xv[7][XSEL][m], cmk(y3.z, y3.w)));                     \
      cplx E2 = cmk(0.5f*S.x, 0.5f*S.y);                                       \
      cplx O2 = cmul(wp, E2);                                                  \
      ZD[t2] = cmk(E2.x - O2.y, E2.y + O2.x);                                  \
      float mx = E2.x + O2.y;                                                  \
      float my = O2.x - E2.y;                                                  \
      mx = __shfl(mx, (SRCLANE));                                              \
      my = __shfl(my, (SRCLANE));                                              \
      ZM[15 - t2] = cmk(mx, my);                                               \
      wp = cmul(wp, stp);                                                      \
    }                                                                          \
  } while (0)

  if (p == 0) {
    // q=0: mirror map is pos 256-m (not 255-m) -> src lane (16-j)&15 and a
    // one-slot shift fixup on lane j==0, plus explicit k=32768 boundary bin.
    int src0 = (t & ~15) | ((16 - j) & 15);
    MAC_PASS(0, 0, zA, zA, src0);
    if (j == 0) {
      zA[15] = zA[14]; zA[14] = zA[13]; zA[13] = zA[12]; zA[12] = zA[11];
      zA[11] = zA[10]; zA[10] = zA[9];  zA[9]  = zA[8];
      const float4* yv = reinterpret_cast<const float4*>(Y2 + (long)128*128 + f*8);
      float4 y0 = yv[0], y1 = yv[1], y2 = yv[2], y3 = yv[3];
      cplx S = cmulj(Xv[0][1][128], cmk(y0.x, y0.y));
      S = cadd(S, cmulj(Xv[1][1][128], cmk(y0.z, y0.w)));
      S = cadd(S, cmulj(Xv[2][1][128], cmk(y1.x, y1.y)));
      S = cadd(S, cmulj(Xv[3][1][128], cmk(y1.z, y1.w)));
      S = cadd(S, cmulj(Xv[4][1][128], cmk(y2.x, y2.y)));
      S = cadd(S, cmulj(Xv[5][1][128], cmk(y2.z, y2.w)));
      S = cadd(S, cmulj(Xv[6][1][128], cmk(y3.x, y3.y)));
      S = cadd(S, cmulj(Xv[7][1][128], cmk(y3.z, y3.w)));
      zA[8] = cmk(S.x, -S.y);
    }
  } else if (selfp) {            // p == 128
    MAC_PASS(128, 0, zA, zA, t ^ 15);
  } else {
    MAC_PASS(cLo, 0, zA, zB, t ^ 15);
    MAC_PASS(cHi, 1, zB, zA, t ^ 15);
  }
#undef MAC_PASS

  __syncthreads();               // X reads done; Ts rows 0..7 reusable below

  // ---- inverse inner DFT-256 over k2 + big twiddle + store ----
#define INV_STORE(Z, MCOL)                                                     \
  do {                                                                         \
    dft16<1>(Z);                                                               \
    {                                                                          \
      float sn_, cs_;                                                          \
      __sincosf(6.28318530717958648f * (float)j * (1.0f/256.0f), &sn_, &cs_);  \
      cplx rr = cmk(cs_, sn_), cur = rr;                                       \
      _Pragma("unroll")                                                        \
      for (int t1 = 1; t1 < 16; ++t1) { Z[t1] = cmul(Z[t1], cur); cur = cmul(cur, rr); } \
    }                                                                          \
    _Pragma("unroll")                                                          \
    for (int t1 = 0; t1 < 16; ++t1) Ts[g][t1*16 + ((j + t1) & 15)] = Z[t1];    \
    _Pragma("unroll")                                                          \
    for (int a2 = 0; a2 < 16; ++a2) Z[a2] = Ts[g][j*16 + ((a2 + j) & 15)];     \
    dft16<1>(Z);                                                               \
    {                                                                          \
      float sn_, cs_;                                                          \
      __sincosf(6.28318530717958648f * (float)((MCOL)*j) * (1.0f/65536.0f), &sn_, &cs_); \
      cplx cur = cmk(cs_, sn_);                                                \
      __sincosf(6.28318530717958648f * (float)(MCOL) * (1.0f/4096.0f), &sn_, &cs_); \
      cplx stp2 = cmk(cs_, sn_);                                               \
      cplx* dst = T2 + (long)(ln*16 + f) * NFFT + (long)(MCOL) * 256;          \
      _Pragma("unroll")                                                        \
      for (int t2 = 0; t2 < 16; ++t2) {                                        \
        dst[j + 16*t2] = cmul(Z[t2], cur);                                     \
        cur = cmul(cur, stp2);                                                 \
      }                                                                        \
    }                                                                          \
  } while (0)

  INV_STORE(zA, cLo);
  if (!selfp) INV_STORE(zB, cHi);
#undef INV_STORE
}

} // namespace

extern "C" void kernel_launch(void* const* d_in, const int* in_sizes, int n_in,
                              void* d_out, int out_size, void* d_ws, size_t ws_size,
                              hipStream_t stream) {
  const cplx*  x    = (const cplx*)d_in[0];   // (32,8,65536) f32 = 32768 cplx/seq
  const float* wgt  = (const float*)d_in[1];  // (16,8,128)
  const float* bias = (const float*)d_in[2];  // (16,)
  float* out = (float*)d_out;                 // (32,16,65409)

  // Workspace: Y2 (33.8 MB) + T1 (Bn*4 MB) + T2 (Bn*8 MB).
  static const int BnOpt[5] = {16, 8, 4, 2, 1};
  int Bn = 1;
  for (int i = 0; i < 5; ++i) {
    size_t need = Y2BYTES + (size_t)BnOpt[i] * 12582912ull;
    if (need <= ws_size) { Bn = BnOpt[i]; break; }
  }
  char* ws = (char*)d_ws;
  cplx* Y2 = (cplx*)ws;
  cplx* T1 = (cplx*)(ws + Y2BYTES);
  cplx* T2 = (cplx*)(ws + Y2BYTES + (size_t)Bn * 4194304ull);

  weight_spec<<<dim3(256, 8), dim3(256), 0, stream>>>(wgt, Y2);

  for (int n0 = 0; n0 < 32; n0 += Bn) {
    fft_pass_a<-1><<<dim3(Bn*8*16), dim3(256), 0, stream>>>(
        x + (long)n0*8*32768, 32768, 32768, T1);
    if (Bn == 16)
      fused_mid<<<dim3(8, 258), dim3(256), 0, stream>>>(T1, Y2, T2, 1);
    else
      fused_mid<<<dim3(Bn, 129), dim3(256), 0, stream>>>(T1, Y2, T2, 0);
    fft_pass_b<1,1><<<dim3(Bn*16*16), dim3(256), 0, stream>>>(
        T2, (cplx*)nullptr, out, bias, n0*16);
  }
}

// Round 5
// 617.737 us; speedup vs baseline: 1.8143x; 1.8143x over previous
//
#include <hip/hip_runtime.h>

namespace {

constexpr int NFFT  = 65536;   // complex FFT length (half of 131072)
constexpr int OUTW  = 65409;   // W - K + 1
// Y2[k1][f][m][c] : weight rfft spectrum, filter-panel layout for the MAC
constexpr size_t Y2BYTES = (size_t)256 * 16 * 129 * 8 * 8;

typedef float2 cplx;

__device__ __forceinline__ cplx cmk(float x, float y){ return make_float2(x, y); }
__device__ __forceinline__ cplx cadd(cplx a, cplx b){ return cmk(a.x+b.x, a.y+b.y); }
__device__ __forceinline__ cplx csub(cplx a, cplx b){ return cmk(a.x-b.x, a.y-b.y); }
__device__ __forceinline__ cplx cmul(cplx a, cplx b){ return cmk(a.x*b.x - a.y*b.y, a.x*b.y + a.y*b.x); }
__device__ __forceinline__ cplx cmulj(cplx a, cplx b){ // a * conj(b)
  return cmk(a.x*b.x + a.y*b.y, a.y*b.x - a.x*b.y); }

// 16-point complex DFT, natural order in/out. DIR=-1 forward, +1 inverse (unnormalized).
template<int DIR>
__device__ __forceinline__ void dft16(cplx v[16]) {
  const float C1 = 0.92387953251128674f;
  const float S1 = 0.38268343236508977f;
  const float C2 = 0.70710678118654752f;
  const float WR[16]  = {1.f, C1, C2, S1, 0.f, -S1, -C2, -C1, -1.f, -C1, -C2, -S1, 0.f, S1, C2, C1};
  const float WIF[16] = {0.f, -S1, -C2, -C1, -1.f, -C1, -C2, -S1, 0.f, S1, C2, C1, 1.f, C1, C2, S1};
  cplx s[16];
  #pragma unroll
  for (int n2 = 0; n2 < 4; ++n2) {
    cplx a = v[n2], b = v[n2+4], c = v[n2+8], d = v[n2+12];
    cplx ac = cadd(a,c), am = csub(a,c), bd = cadd(b,d), bm = csub(b,d);
    cplx x0 = cadd(ac, bd), x2 = csub(ac, bd), x1, x3;
    if (DIR == -1) { x1 = cmk(am.x + bm.y, am.y - bm.x); x3 = cmk(am.x - bm.y, am.y + bm.x); }
    else           { x1 = cmk(am.x - bm.y, am.y + bm.x); x3 = cmk(am.x + bm.y, am.y - bm.x); }
    s[0*4+n2] = x0;
    {
      int e1 = (n2*1) & 15, e2 = (n2*2) & 15, e3 = (n2*3) & 15;
      cplx w1 = cmk(WR[e1], (DIR==-1)? WIF[e1] : -WIF[e1]);
      cplx w2 = cmk(WR[e2], (DIR==-1)? WIF[e2] : -WIF[e2]);
      cplx w3 = cmk(WR[e3], (DIR==-1)? WIF[e3] : -WIF[e3]);
      s[1*4+n2] = cmul(x1, w1);
      s[2*4+n2] = cmul(x2, w2);
      s[3*4+n2] = cmul(x3, w3);
    }
  }
  #pragma unroll
  for (int t1 = 0; t1 < 4; ++t1) {
    cplx a = s[t1*4+0], b = s[t1*4+1], c = s[t1*4+2], d = s[t1*4+3];
    cplx ac = cadd(a,c), am = csub(a,c), bd = cadd(b,d), bm = csub(b,d);
    cplx x0 = cadd(ac,bd), x2 = csub(ac,bd), x1, x3;
    if (DIR == -1) { x1 = cmk(am.x + bm.y, am.y - bm.x); x3 = cmk(am.x - bm.y, am.y + bm.x); }
    else           { x1 = cmk(am.x - bm.y, am.y + bm.x); x3 = cmk(am.x + bm.y, am.y - bm.x); }
    v[t1+0] = x0; v[t1+4] = x1; v[t1+8] = x2; v[t1+12] = x3;
  }
}

// Four-step pass A (forward): inner 256-pt DFTs + big twiddle.
// k1-major output staged through padded LDS so global stores are contiguous.
template<int DIR>
__global__ __launch_bounds__(256)
void fft_pass_a(const cplx* __restrict__ in, long inStride, int inLen,
                cplx* __restrict__ T) {
  int blk = blockIdx.x;
  int seq = blk >> 4;
  int B0  = (blk & 15) << 4;
  int t = threadIdx.x;
  __shared__ cplx sm[4608];                    // 36864 B: union of two views
  cplx (*tile)[260] = (cplx(*)[260])sm;        // phase-1 view [16][260]
  cplx* tile2 = sm;                            // phase-2 view [256][18]
  {
    const cplx* src = in + (long)seq * inStride;
    int cb = t & 15, rg = t >> 4;
    #pragma unroll
    for (int i = 0; i < 16; ++i) {
      int a = i*16 + rg;
      int sIdx = a*256 + B0 + cb;
      cplx v = (sIdx < inLen) ? src[sIdx] : cmk(0.f, 0.f);
      tile[cb][a] = v;
    }
  }
  __syncthreads();
  int cc = t >> 4, j = t & 15;
  cplx x[16];
  #pragma unroll
  for (int a1 = 0; a1 < 16; ++a1) x[a1] = tile[cc][a1*16 + j];
  dft16<DIR>(x);
  {
    float sn, cs;
    __sincosf((float)DIR * 6.28318530717958648f * (float)j * (1.0f/256.0f), &sn, &cs);
    cplx r = cmk(cs, sn), cur = r;
    #pragma unroll
    for (int t1 = 1; t1 < 16; ++t1) { x[t1] = cmul(x[t1], cur); cur = cmul(cur, r); }
  }
  __syncthreads();
  #pragma unroll
  for (int t1 = 0; t1 < 16; ++t1) tile[cc][t1*16 + ((j + t1) & 15)] = x[t1];
  __syncthreads();
  #pragma unroll
  for (int a2 = 0; a2 < 16; ++a2) x[a2] = tile[cc][j*16 + ((a2 + j) & 15)];
  dft16<DIR>(x);
  int b = B0 + cc;
  __syncthreads();   // tile reads done; reuse as tile2
  {
    float sn, cs;
    __sincosf((float)DIR * 6.28318530717958648f * (float)(b*j) * (1.0f/65536.0f), &sn, &cs);
    cplx cur = cmk(cs, sn);
    __sincosf((float)DIR * 6.28318530717958648f * (float)b * (1.0f/4096.0f), &sn, &cs);
    cplx stp = cmk(cs, sn);
    #pragma unroll
    for (int t2 = 0; t2 < 16; ++t2) {
      tile2[(j + 16*t2)*18 + cc] = cmul(x[t2], cur);
      cur = cmul(cur, stp);
    }
  }
  __syncthreads();
  {
    int rg = t >> 4, cb = t & 15;
    cplx* dst = T + (long)seq * NFFT + B0 + cb;
    #pragma unroll
    for (int i = 0; i < 16; ++i) {
      int k1 = i*16 + rg;
      dst[(long)k1 * 256] = tile2[k1*18 + cb];
    }
  }
}

// Four-step pass B: outer 256-pt DFTs. MODE 1 = inverse-final with bias+trunc.
template<int DIR, int MODE>
__global__ __launch_bounds__(256)
void fft_pass_b(const cplx* __restrict__ T, cplx* __restrict__ outZ,
                float* __restrict__ outR, const float* __restrict__ bias,
                int seqBase) {
  int blk = blockIdx.x;
  int seq = blk >> 4;
  int K0  = (blk & 15) << 4;
  int t = threadIdx.x;
  __shared__ cplx tile[16][260];
  {
    const cplx* src = T + (long)seq * NFFT;
    int ck = t & 15, rg = t >> 4;
    #pragma unroll
    for (int i = 0; i < 16; ++i) {
      int b = i*16 + rg;
      tile[ck][b] = src[b*256 + K0 + ck];
    }
  }
  __syncthreads();
  int cc = t >> 4, j = t & 15;
  cplx x[16];
  #pragma unroll
  for (int a1 = 0; a1 < 16; ++a1) x[a1] = tile[cc][a1*16 + j];
  dft16<DIR>(x);
  {
    float sn, cs;
    __sincosf((float)DIR * 6.28318530717958648f * (float)j * (1.0f/256.0f), &sn, &cs);
    cplx r = cmk(cs, sn), cur = r;
    #pragma unroll
    for (int t1 = 1; t1 < 16; ++t1) { x[t1] = cmul(x[t1], cur); cur = cmul(cur, r); }
  }
  __syncthreads();
  #pragma unroll
  for (int t1 = 0; t1 < 16; ++t1) tile[cc][t1*16 + ((j + t1) & 15)] = x[t1];
  __syncthreads();
  #pragma unroll
  for (int a2 = 0; a2 < 16; ++a2) x[a2] = tile[cc][j*16 + ((a2 + j) & 15)];
  dft16<DIR>(x);
  __syncthreads();
  #pragma unroll
  for (int t2 = 0; t2 < 16; ++t2) tile[cc][j + 16*t2] = x[t2];
  __syncthreads();
  int ck2 = t & 15, rg2 = t >> 4;
  if (MODE == 0) {
    cplx* dst = outZ + (long)seq * NFFT + K0 + ck2;
    #pragma unroll
    for (int i = 0; i < 16; ++i) {
      int k2 = i*16 + rg2;
      dst[256*k2] = tile[ck2][k2];
    }
  } else {
    const float sc = 1.0f / 65536.0f;
    int gseq = seqBase + seq;
    float bf = bias[gseq & 15];
    float* dst = outR + (long)gseq * OUTW;
    #pragma unroll
    for (int i = 0; i < 16; ++i) {
      int k2 = i*16 + rg2;
      int s  = K0 + ck2 + 256*k2;
      int tp = 2*s;
      cplx v = tile[ck2][k2];
      if (tp < OUTW)     dst[tp]   = v.x * sc + bf;
      if (tp + 1 < OUTW) dst[tp+1] = v.y * sc + bf;
    }
  }
}

// Direct weight rfft into panel layout Y2[k1][f][m][c], k = k1 + 256*m.
__global__ __launch_bounds__(256)
void weight_spec(const float* __restrict__ wgt, cplx* __restrict__ Y2) {
  const int k1 = blockIdx.x;      // 0..255
  const int fg = blockIdx.y;      // 0..7
  const int t  = threadIdx.x;
  __shared__ float wt[16][129];
  for (int e = t; e < 16*128; e += 256)
    wt[e >> 7][e & 127] = wgt[(fg*16 + (e >> 7))*128 + (e & 127)];
  __syncthreads();
  const int fcL = t & 15;
  const int fc  = fg*16 + fcL;
  const int f   = fc >> 3;
  const int cch = fc & 7;
  for (int m = t >> 4; m < 129; m += 16) {
    int k = k1 + 256*m;
    if (k > 32768) break;
    float sn, cs;
    __sincosf(-3.14159265358979324f * (float)k * (1.0f/65536.0f), &sn, &cs);
    cplx r  = cmk(cs, sn);
    cplx r2 = cmul(r, r);
    cplx r4 = cmul(r2, r2);
    cplx r8 = cmul(r4, r4);
    cplx av[8];
    #pragma unroll
    for (int v = 0; v < 8; ++v) av[v] = cmk(0.f, 0.f);
    cplx C = cmk(1.f, 0.f);
    #pragma unroll
    for (int u = 0; u < 16; ++u) {
      #pragma unroll
      for (int v = 0; v < 8; ++v) {
        float w = wt[fcL][u*8 + v];
        av[v].x += w * C.x;
        av[v].y += w * C.y;
      }
      C = cmul(C, r8);
    }
    cplx acc = av[7];
    #pragma unroll
    for (int v = 6; v >= 0; --v) acc = cadd(av[v], cmul(r, acc));
    Y2[(((long)k1*16 + f)*129 + m)*8 + cch] = acc;
  }
}

// Fused middle stage v5.
//  - Xs merged into the Ts LDS region: LDS 33280 B => 4 blocks/CU.
//  - NO launch-bounds cap (rounds 2 & 4 proved caps => allocator snaps to a
//    64/128/256 tier and spills ~650 MB). Registers shaved structurally:
//    no manual Y2 prefetch (16 VGPRs), panel Y2 layout (fewer addr regs).
//  - XCD-aware remap (remap=1, Bn=16): XCD = dispatch%8 = blockIdx.x; each
//    XCD runs 16 consecutive same-p blocks so its ~132-KB Y2 panel pair is
//    reused 16x out of the private 4-MB L2.
__global__ __launch_bounds__(256)
void fused_mid(const cplx* __restrict__ T1, const cplx* __restrict__ Y2,
               cplx* __restrict__ T2, int remap) {
  int p, ln;
  if (remap) {
    int xcd = blockIdx.x;              // 0..7 (= dispatch index % 8)
    int y   = blockIdx.y;              // 0..257
    if (y < 256) { p = xcd + 8*(y >> 4); ln = y & 15; }
    else         { p = 128;            ln = ((y - 256) << 3) | xcd; }
  } else {
    ln = blockIdx.x;
    p  = blockIdx.y;
  }
  const int cLo = p;
  const int cHi = (256 - p) & 255;
  const bool selfp = (p == 0) || (p == 128);
  const int t = threadIdx.x;
  const int g = t >> 4;                // 16 groups of 16 lanes (wave-aligned)
  const int j = t & 15;
  const int c = g & 7;
  const int half = g >> 3;
  const int col = half ? cHi : cLo;

  __shared__ cplx sm[16*260];          // 33280 B, two views:
  cplx (*Ts)[260]      = (cplx(*)[260])sm;       // transpose / Z-exchange
  cplx (*Xv)[2][130]   = (cplx(*)[2][130])sm;    // X view = Ts rows 0..7

  const float C16 = 0.98078528040323044913f;  // cos(pi/16)
  const float S16 = 0.19509032201612826785f;  // sin(pi/16)

  // ---- Phase F: forward DFT-256 over b, one column per group-half ----
  cplx x[16];
  {
    const cplx* src = T1 + ((long)(ln*8 + c) * NFFT + (long)col * 256);
    #pragma unroll
    for (int a1 = 0; a1 < 16; ++a1) x[a1] = src[a1*16 + j];
  }
  dft16<-1>(x);
  {
    float sn, cs;
    __sincosf(-6.28318530717958648f * (float)j * (1.0f/256.0f), &sn, &cs);
    cplx r = cmk(cs, sn), cur = r;
    #pragma unroll
    for (int t1 = 1; t1 < 16; ++t1) { x[t1] = cmul(x[t1], cur); cur = cmul(cur, r); }
  }
  #pragma unroll
  for (int t1 = 0; t1 < 16; ++t1) Ts[g][t1*16 + ((j + t1) & 15)] = x[t1];
  #pragma unroll
  for (int a2 = 0; a2 < 16; ++a2) x[a2] = Ts[g][j*16 + ((a2 + j) & 15)];
  dft16<-1>(x);
  #pragma unroll
  for (int t2 = 0; t2 < 16; ++t2) Ts[g][j + 16*t2] = x[t2];
  __syncthreads();

  // ---- stage mirror Z to registers, then overwrite Ts rows 0..7 with X ----
  cplx zmr[8];
  #pragma unroll
  for (int t2 = 0; t2 < 8; ++t2) {
    int m = j + 16*t2;
    int k = col + 256*m;
    int mi = (65536 - k) & 65535;
    zmr[t2] = Ts[g ^ 8][mi >> 8];
  }
  __syncthreads();                     // all Z reads done; Ts rows 0..7 free
  {
    float sn, cs;
    __sincosf(-3.14159265358979324f * (float)(col + 256*j) * (1.0f/65536.0f), &sn, &cs);
    cplx w = cmk(cs, sn);
    const cplx stp = cmk(C16, -S16);
    #pragma unroll
    for (int t2 = 0; t2 < 8; ++t2) {
      int m = j + 16*t2;
      cplx zk = x[t2];
      cplx zm = zmr[t2];
      cplx E = cmk(0.5f*(zk.x + zm.x), 0.5f*(zk.y - zm.y));
      cplx D = cmk(zk.x - zm.x, zk.y + zm.y);
      cplx O = cmk(0.5f*D.y, -0.5f*D.x);
      Xv[c][half][m] = cadd(E, cmul(w, O));
      w = cmul(w, stp);
    }
  }
  if (p == 0 && half == 0 && j == 0) {
    cplx zk = x[8];
    cplx X = cmk(zk.x, -zk.y);
    Xv[c][0][128] = X;
    Xv[c][1][128] = X;
  }
  __syncthreads();

  // ---- Phase M: one MAC per bin, pack twice, shfl the mirror half ----
  const int f = g;
  cplx zA[16], zB[16];

#define MAC_PASS(Q, XSEL, ZD, ZM, SRCLANE)                                     \
  do {                                                                         \
    const int q_ = (Q);                                                        \
    float sn_, cs_;                                                            \
    __sincosf(3.14159265358979324f * (float)(q_ + 256*j) * (1.0f/65536.0f),    \
              &sn_, &cs_);                                                     \
    cplx wp = cmk(cs_, sn_);                                                   \
    const cplx stp = cmk(C16, S16);                                            \
    const float4* yb = reinterpret_cast<const float4*>(                        \
        Y2 + (((long)q_*16 + f)*129 + j)*8);                                   \
    _Pragma("unroll")                                                          \
    for (int t2 = 0; t2 < 8; ++t2) {                                           \
      const float4* yv = yb + (long)t2*64;                                     \
      float4 y0 = yv[0], y1 = yv[1], y2 = yv[2], y3 = yv[3];                   \
      int m = j + 16*t2;                                                       \
      cplx S = cmulj(Xv[0][XSEL][m], cmk(y0.x, y0.y));                         \
      S = cadd(S, cmulj(Xv[1][XSEL][m], cmk(y0.z, y0.w)));                     \
      S = cadd(S, cmulj(Xv[2][XSEL][m], cmk(y1.x, y1.y)));                     \
      S = cadd(S, cmulj(Xv[3][XSEL][m], cmk(y1.z, y1.w)));                     \
      S = cadd(S, cmulj(Xv[4][XSEL][m], cmk(y2.x, y2.y)));                     \
      S = cadd(S, cmulj(Xv[5][XSEL][m], cmk(y2.z, y2.w)));                     \
      S = cadd(S, cmulj(Xv[6][XSEL][m], cmk(y3.x, y3.y)));                     \
      S = cadd(S, cmulj(Xv[7][XSEL][m], cmk(y3.z, y3.w)));                     \
      cplx E2 = cmk(0.5f*S.x, 0.5f*S.y);                                       \
      cplx O2 = cmul(wp, E2);                                                  \
      ZD[t2] = cmk(E2.x - O2.y, E2.y + O2.x);                                  \
      float mx = E2.x + O2.y;                                                  \
      float my = O2.x - E2.y;                                                  \
      mx = __shfl(mx, (SRCLANE));                                              \
      my = __shfl(my, (SRCLANE));                                              \
      ZM[15 - t2] = cmk(mx, my);                                               \
      wp = cmul(wp, stp);                                                      \
    }                                                                          \
  } while (0)

  if (p == 0) {
    // q=0: mirror map is pos 256-m (not 255-m) -> src lane (16-j)&15 and a
    // one-slot shift fixup on lane j==0, plus explicit k=32768 boundary bin.
    int src0 = (t & ~15) | ((16 - j) & 15);
    MAC_PASS(0, 0, zA, zA, src0);
    if (j == 0) {
      zA[15] = zA[14]; zA[14] = zA[13]; zA[13] = zA[12]; zA[12] = zA[11];
      zA[11] = zA[10]; zA[10] = zA[9];  zA[9]  = zA[8];
      const float4* yv = reinterpret_cast<const float4*>(
          Y2 + ((long)f*129 + 128)*8);
      float4 y0 = yv[0], y1 = yv[1], y2 = yv[2], y3 = yv[3];
      cplx S = cmulj(Xv[0][1][128], cmk(y0.x, y0.y));
      S = cadd(S, cmulj(Xv[1][1][128], cmk(y0.z, y0.w)));
      S = cadd(S, cmulj(Xv[2][1][128], cmk(y1.x, y1.y)));
      S = cadd(S, cmulj(Xv[3][1][128], cmk(y1.z, y1.w)));
      S = cadd(S, cmulj(Xv[4][1][128], cmk(y2.x, y2.y)));
      S = cadd(S, cmulj(Xv[5][1][128], cmk(y2.z, y2.w)));
      S = cadd(S, cmulj(Xv[6][1][128], cmk(y3.x, y3.y)));
      S = cadd(S, cmulj(Xv[7][1][128], cmk(y3.z, y3.w)));
      zA[8] = cmk(S.x, -S.y);
    }
  } else if (selfp) {            // p == 128
    MAC_PASS(128, 0, zA, zA, t ^ 15);
  } else {
    MAC_PASS(cLo, 0, zA, zB, t ^ 15);
    MAC_PASS(cHi, 1, zB, zA, t ^ 15);
  }
#undef MAC_PASS

  __syncthreads();               // X reads done; Ts rows 0..7 reusable below

  // ---- inverse inner DFT-256 over k2 + big twiddle + store ----
#define INV_STORE(Z, MCOL)                                                     \
  do {                                                                         \
    dft16<1>(Z);                                                               \
    {                                                                          \
      float sn_, cs_;                                                          \
      __sincosf(6.28318530717958648f * (float)j * (1.0f/256.0f), &sn_, &cs_);  \
      cplx rr = cmk(cs_, sn_), cur = rr;                                       \
      _Pragma("unroll")                                                        \
      for (int t1 = 1; t1 < 16; ++t1) { Z[t1] = cmul(Z[t1], cur); cur = cmul(cur, rr); } \
    }                                                                          \
    _Pragma("unroll")                                                          \
    for (int t1 = 0; t1 < 16; ++t1) Ts[g][t1*16 + ((j + t1) & 15)] = Z[t1];    \
    _Pragma("unroll")                                                          \
    for (int a2 = 0; a2 < 16; ++a2) Z[a2] = Ts[g][j*16 + ((a2 + j) & 15)];     \
    dft16<1>(Z);                                                               \
    {                                                                          \
      float sn_, cs_;                                                          \
      __sincosf(6.28318530717958648f * (float)((MCOL)*j) * (1.0f/65536.0f), &sn_, &cs_); \
      cplx cur = cmk(cs_, sn_);                                                \
      __sincosf(6.28318530717958648f * (float)(MCOL) * (1.0f/4096.0f), &sn_, &cs_); \
      cplx stp2 = cmk(cs_, sn_);                                               \
      cplx* dst = T2 + (long)(ln*16 + f) * NFFT + (long)(MCOL) * 256;          \
      _Pragma("unroll")                                                        \
      for (int t2 = 0; t2 < 16; ++t2) {                                        \
        dst[j + 16*t2] = cmul(Z[t2], cur);                                     \
        cur = cmul(cur, stp2);                                                 \
      }                                                                        \
    }                                                                          \
  } while (0)

  INV_STORE(zA, cLo);
  if (!selfp) INV_STORE(zB, cHi);
#undef INV_STORE
}

} // namespace

extern "C" void kernel_launch(void* const* d_in, const int* in_sizes, int n_in,
                              void* d_out, int out_size, void* d_ws, size_t ws_size,
                              hipStream_t stream) {
  const cplx*  x    = (const cplx*)d_in[0];   // (32,8,65536) f32 = 32768 cplx/seq
  const float* wgt  = (const float*)d_in[1];  // (16,8,128)
  const float* bias = (const float*)d_in[2];  // (16,)
  float* out = (float*)d_out;                 // (32,16,65409)

  // Workspace: Y2 (33.8 MB) + T1 (Bn*4 MB) + T2 (Bn*8 MB).
  static const int BnOpt[5] = {16, 8, 4, 2, 1};
  int Bn = 1;
  for (int i = 0; i < 5; ++i) {
    size_t need = Y2BYTES + (size_t)BnOpt[i] * 12582912ull;
    if (need <= ws_size) { Bn = BnOpt[i]; break; }
  }
  char* ws = (char*)d_ws;
  cplx* Y2 = (cplx*)ws;
  cplx* T1 = (cplx*)(ws + Y2BYTES);
  cplx* T2 = (cplx*)(ws + Y2BYTES + (size_t)Bn * 4194304ull);

  weight_spec<<<dim3(256, 8), dim3(256), 0, stream>>>(wgt, Y2);

  for (int n0 = 0; n0 < 32; n0 += Bn) {
    fft_pass_a<-1><<<dim3(Bn*8*16), dim3(256), 0, stream>>>(
        x + (long)n0*8*32768, 32768, 32768, T1);
    if (Bn == 16)
      fused_mid<<<dim3(8, 258), dim3(256), 0, stream>>>(T1, Y2, T2, 1);
    else
      fused_mid<<<dim3(Bn, 129), dim3(256), 0, stream>>>(T1, Y2, T2, 0);
    fft_pass_b<1,1><<<dim3(Bn*16*16), dim3(256), 0, stream>>>(
        T2, (cplx*)nullptr, out, bias, n0*16);
  }
}

// Round 7
// 553.758 us; speedup vs baseline: 2.0239x; 1.1155x over previous
//
#include <hip/hip_runtime.h>

namespace {

constexpr int NFFT  = 65536;   // complex FFT length (half of 131072)
constexpr int OUTW  = 65409;   // W - K + 1
// Y2[k1][f][m][c] : weight rfft spectrum, filter-panel layout for the MAC
constexpr size_t Y2BYTES = (size_t)256 * 16 * 129 * 8 * 8;

typedef float2 cplx;

__device__ __forceinline__ cplx cmk(float x, float y){ return make_float2(x, y); }
__device__ __forceinline__ cplx cadd(cplx a, cplx b){ return cmk(a.x+b.x, a.y+b.y); }
__device__ __forceinline__ cplx csub(cplx a, cplx b){ return cmk(a.x-b.x, a.y-b.y); }
__device__ __forceinline__ cplx cmul(cplx a, cplx b){ return cmk(a.x*b.x - a.y*b.y, a.x*b.y + a.y*b.x); }
__device__ __forceinline__ cplx cmulj(cplx a, cplx b){ // a * conj(b)
  return cmk(a.x*b.x + a.y*b.y, a.y*b.x - a.x*b.y); }

// 16-point complex DFT, natural order in/out. DIR=-1 forward, +1 inverse (unnormalized).
template<int DIR>
__device__ __forceinline__ void dft16(cplx v[16]) {
  const float C1 = 0.92387953251128674f;
  const float S1 = 0.38268343236508977f;
  const float C2 = 0.70710678118654752f;
  const float WR[16]  = {1.f, C1, C2, S1, 0.f, -S1, -C2, -C1, -1.f, -C1, -C2, -S1, 0.f, S1, C2, C1};
  const float WIF[16] = {0.f, -S1, -C2, -C1, -1.f, -C1, -C2, -S1, 0.f, S1, C2, C1, 1.f, C1, C2, S1};
  cplx s[16];
  #pragma unroll
  for (int n2 = 0; n2 < 4; ++n2) {
    cplx a = v[n2], b = v[n2+4], c = v[n2+8], d = v[n2+12];
    cplx ac = cadd(a,c), am = csub(a,c), bd = cadd(b,d), bm = csub(b,d);
    cplx x0 = cadd(ac, bd), x2 = csub(ac, bd), x1, x3;
    if (DIR == -1) { x1 = cmk(am.x + bm.y, am.y - bm.x); x3 = cmk(am.x - bm.y, am.y + bm.x); }
    else           { x1 = cmk(am.x - bm.y, am.y + bm.x); x3 = cmk(am.x + bm.y, am.y - bm.x); }
    s[0*4+n2] = x0;
    {
      int e1 = (n2*1) & 15, e2 = (n2*2) & 15, e3 = (n2*3) & 15;
      cplx w1 = cmk(WR[e1], (DIR==-1)? WIF[e1] : -WIF[e1]);
      cplx w2 = cmk(WR[e2], (DIR==-1)? WIF[e2] : -WIF[e2]);
      cplx w3 = cmk(WR[e3], (DIR==-1)? WIF[e3] : -WIF[e3]);
      s[1*4+n2] = cmul(x1, w1);
      s[2*4+n2] = cmul(x2, w2);
      s[3*4+n2] = cmul(x3, w3);
    }
  }
  #pragma unroll
  for (int t1 = 0; t1 < 4; ++t1) {
    cplx a = s[t1*4+0], b = s[t1*4+1], c = s[t1*4+2], d = s[t1*4+3];
    cplx ac = cadd(a,c), am = csub(a,c), bd = cadd(b,d), bm = csub(b,d);
    cplx x0 = cadd(ac,bd), x2 = csub(ac,bd), x1, x3;
    if (DIR == -1) { x1 = cmk(am.x + bm.y, am.y - bm.x); x3 = cmk(am.x - bm.y, am.y + bm.x); }
    else           { x1 = cmk(am.x - bm.y, am.y + bm.x); x3 = cmk(am.x + bm.y, am.y - bm.x); }
    v[t1+0] = x0; v[t1+4] = x1; v[t1+8] = x2; v[t1+12] = x3;
  }
}

// Four-step pass A (forward): inner 256-pt DFTs + big twiddle.
// k1-major output staged through padded LDS so global stores are contiguous.
template<int DIR>
__global__ __launch_bounds__(256)
void fft_pass_a(const cplx* __restrict__ in, long inStride, int inLen,
                cplx* __restrict__ T) {
  int blk = blockIdx.x;
  int seq = blk >> 4;
  int B0  = (blk & 15) << 4;
  int t = threadIdx.x;
  __shared__ cplx sm[4608];                    // 36864 B: union of two views
  cplx (*tile)[260] = (cplx(*)[260])sm;        // phase-1 view [16][260]
  cplx* tile2 = sm;                            // phase-2 view [256][18]
  {
    const cplx* src = in + (long)seq * inStride;
    int cb = t & 15, rg = t >> 4;
    #pragma unroll
    for (int i = 0; i < 16; ++i) {
      int a = i*16 + rg;
      int sIdx = a*256 + B0 + cb;
      cplx v = (sIdx < inLen) ? src[sIdx] : cmk(0.f, 0.f);
      tile[cb][a] = v;
    }
  }
  __syncthreads();
  int cc = t >> 4, j = t & 15;
  cplx x[16];
  #pragma unroll
  for (int a1 = 0; a1 < 16; ++a1) x[a1] = tile[cc][a1*16 + j];
  dft16<DIR>(x);
  {
    float sn, cs;
    __sincosf((float)DIR * 6.28318530717958648f * (float)j * (1.0f/256.0f), &sn, &cs);
    cplx r = cmk(cs, sn), cur = r;
    #pragma unroll
    for (int t1 = 1; t1 < 16; ++t1) { x[t1] = cmul(x[t1], cur); cur = cmul(cur, r); }
  }
  __syncthreads();
  #pragma unroll
  for (int t1 = 0; t1 < 16; ++t1) tile[cc][t1*16 + ((j + t1) & 15)] = x[t1];
  __syncthreads();
  #pragma unroll
  for (int a2 = 0; a2 < 16; ++a2) x[a2] = tile[cc][j*16 + ((a2 + j) & 15)];
  dft16<DIR>(x);
  int b = B0 + cc;
  __syncthreads();   // tile reads done; reuse as tile2
  {
    float sn, cs;
    __sincosf((float)DIR * 6.28318530717958648f * (float)(b*j) * (1.0f/65536.0f), &sn, &cs);
    cplx cur = cmk(cs, sn);
    __sincosf((float)DIR * 6.28318530717958648f * (float)b * (1.0f/4096.0f), &sn, &cs);
    cplx stp = cmk(cs, sn);
    #pragma unroll
    for (int t2 = 0; t2 < 16; ++t2) {
      tile2[(j + 16*t2)*18 + cc] = cmul(x[t2], cur);
      cur = cmul(cur, stp);
    }
  }
  __syncthreads();
  {
    int rg = t >> 4, cb = t & 15;
    cplx* dst = T + (long)seq * NFFT + B0 + cb;
    #pragma unroll
    for (int i = 0; i < 16; ++i) {
      int k1 = i*16 + rg;
      dst[(long)k1 * 256] = tile2[k1*18 + cb];
    }
  }
}

// Four-step pass B: outer 256-pt DFTs. MODE 1 = inverse-final with bias+trunc.
template<int DIR, int MODE>
__global__ __launch_bounds__(256)
void fft_pass_b(const cplx* __restrict__ T, cplx* __restrict__ outZ,
                float* __restrict__ outR, const float* __restrict__ bias,
                int seqBase) {
  int blk = blockIdx.x;
  int seq = blk >> 4;
  int K0  = (blk & 15) << 4;
  int t = threadIdx.x;
  __shared__ cplx tile[16][260];
  {
    const cplx* src = T + (long)seq * NFFT;
    int ck = t & 15, rg = t >> 4;
    #pragma unroll
    for (int i = 0; i < 16; ++i) {
      int b = i*16 + rg;
      tile[ck][b] = src[b*256 + K0 + ck];
    }
  }
  __syncthreads();
  int cc = t >> 4, j = t & 15;
  cplx x[16];
  #pragma unroll
  for (int a1 = 0; a1 < 16; ++a1) x[a1] = tile[cc][a1*16 + j];
  dft16<DIR>(x);
  {
    float sn, cs;
    __sincosf((float)DIR * 6.28318530717958648f * (float)j * (1.0f/256.0f), &sn, &cs);
    cplx r = cmk(cs, sn), cur = r;
    #pragma unroll
    for (int t1 = 1; t1 < 16; ++t1) { x[t1] = cmul(x[t1], cur); cur = cmul(cur, r); }
  }
  __syncthreads();
  #pragma unroll
  for (int t1 = 0; t1 < 16; ++t1) tile[cc][t1*16 + ((j + t1) & 15)] = x[t1];
  __syncthreads();
  #pragma unroll
  for (int a2 = 0; a2 < 16; ++a2) x[a2] = tile[cc][j*16 + ((a2 + j) & 15)];
  dft16<DIR>(x);
  __syncthreads();
  #pragma unroll
  for (int t2 = 0; t2 < 16; ++t2) tile[cc][j + 16*t2] = x[t2];
  __syncthreads();
  int ck2 = t & 15, rg2 = t >> 4;
  if (MODE == 0) {
    cplx* dst = outZ + (long)seq * NFFT + K0 + ck2;
    #pragma unroll
    for (int i = 0; i < 16; ++i) {
      int k2 = i*16 + rg2;
      dst[256*k2] = tile[ck2][k2];
    }
  } else {
    const float sc = 1.0f / 65536.0f;
    int gseq = seqBase + seq;
    float bf = bias[gseq & 15];
    float* dst = outR + (long)gseq * OUTW;
    #pragma unroll
    for (int i = 0; i < 16; ++i) {
      int k2 = i*16 + rg2;
      int s  = K0 + ck2 + 256*k2;
      int tp = 2*s;
      cplx v = tile[ck2][k2];
      if (tp < OUTW)     dst[tp]   = v.x * sc + bf;
      if (tp + 1 < OUTW) dst[tp+1] = v.y * sc + bf;
    }
  }
}

// Direct weight rfft into panel layout Y2[k1][f][m][c], k = k1 + 256*m.
__global__ __launch_bounds__(256)
void weight_spec(const float* __restrict__ wgt, cplx* __restrict__ Y2) {
  const int k1 = blockIdx.x;      // 0..255
  const int fg = blockIdx.y;      // 0..7
  const int t  = threadIdx.x;
  __shared__ float wt[16][129];
  for (int e = t; e < 16*128; e += 256)
    wt[e >> 7][e & 127] = wgt[(fg*16 + (e >> 7))*128 + (e & 127)];
  __syncthreads();
  const int fcL = t & 15;
  const int fc  = fg*16 + fcL;
  const int f   = fc >> 3;
  const int cch = fc & 7;
  for (int m = t >> 4; m < 129; m += 16) {
    int k = k1 + 256*m;
    if (k > 32768) break;
    float sn, cs;
    __sincosf(-3.14159265358979324f * (float)k * (1.0f/65536.0f), &sn, &cs);
    cplx r  = cmk(cs, sn);
    cplx r2 = cmul(r, r);
    cplx r4 = cmul(r2, r2);
    cplx r8 = cmul(r4, r4);
    cplx av[8];
    #pragma unroll
    for (int v = 0; v < 8; ++v) av[v] = cmk(0.f, 0.f);
    cplx C = cmk(1.f, 0.f);
    #pragma unroll
    for (int u = 0; u < 16; ++u) {
      #pragma unroll
      for (int v = 0; v < 8; ++v) {
        float w = wt[fcL][u*8 + v];
        av[v].x += w * C.x;
        av[v].y += w * C.y;
      }
      C = cmul(C, r8);
    }
    cplx acc = av[7];
    #pragma unroll
    for (int v = 6; v >= 0; --v) acc = cadd(av[v], cmul(r, acc));
    Y2[(((long)k1*16 + f)*129 + m)*8 + cch] = acc;
  }
}

// Fused middle stage v6.
//  - Hybrid mirror path: pass-1 (cLo) mirrors go to LDS (Ts rows 8..15, dead
//    at that point) instead of registers; pass-2 (cHi) keeps the shfl into
//    zA[8..15]. Cuts ~32 live VGPRs at the plateau — target VGPR <= 128
//    (the 129..256 tier halves waves/CU; rounds 2/4 proved launch-bounds
//    caps cause catastrophic spill, so this is done structurally).
//  - 2-deep Y2 prefetch restored (round-3-proven ILP).
//  - XCD-aware remap kept (round-5: FETCH 164 -> 50 MB).
__global__ __launch_bounds__(256)
void fused_mid(const cplx* __restrict__ T1, const cplx* __restrict__ Y2,
               cplx* __restrict__ T2, int remap) {
  int p, ln;
  if (remap) {
    int xcd = blockIdx.x;              // 0..7 (= dispatch index % 8)
    int y   = blockIdx.y;              // 0..257
    if (y < 256) { p = xcd + 8*(y >> 4); ln = y & 15; }
    else         { p = 128;            ln = ((y - 256) << 3) | xcd; }
  } else {
    ln = blockIdx.x;
    p  = blockIdx.y;
  }
  const int cLo = p;
  const int cHi = (256 - p) & 255;
  const bool selfp = (p == 0) || (p == 128);
  const int t = threadIdx.x;
  const int g = t >> 4;                // 16 groups of 16 lanes (wave-aligned)
  const int j = t & 15;
  const int c = g & 7;
  const int half = g >> 3;
  const int col = half ? cHi : cLo;

  __shared__ cplx sm[16*260];          // 33280 B, three views:
  cplx (*Ts)[260]      = (cplx(*)[260])sm;       // transpose / Z-exchange
  cplx (*Xv)[2][130]   = (cplx(*)[2][130])sm;    // X view = Ts rows 0..7
  cplx* mir = &sm[8*260];                        // mirror buf = Ts rows 8..15
                                                 // idx: g*128 + s*16 + j

  const float C16 = 0.98078528040323044913f;  // cos(pi/16)
  const float S16 = 0.19509032201612826785f;  // sin(pi/16)

  // ---- Phase F: forward DFT-256 over b, one column per group-half ----
  cplx x[16];
  {
    const cplx* src = T1 + ((long)(ln*8 + c) * NFFT + (long)col * 256);
    #pragma unroll
    for (int a1 = 0; a1 < 16; ++a1) x[a1] = src[a1*16 + j];
  }
  dft16<-1>(x);
  {
    float sn, cs;
    __sincosf(-6.28318530717958648f * (float)j * (1.0f/256.0f), &sn, &cs);
    cplx r = cmk(cs, sn), cur = r;
    #pragma unroll
    for (int t1 = 1; t1 < 16; ++t1) { x[t1] = cmul(x[t1], cur); cur = cmul(cur, r); }
  }
  #pragma unroll
  for (int t1 = 0; t1 < 16; ++t1) Ts[g][t1*16 + ((j + t1) & 15)] = x[t1];
  #pragma unroll
  for (int a2 = 0; a2 < 16; ++a2) x[a2] = Ts[g][j*16 + ((a2 + j) & 15)];
  dft16<-1>(x);
  #pragma unroll
  for (int t2 = 0; t2 < 16; ++t2) Ts[g][j + 16*t2] = x[t2];
  __syncthreads();

  // ---- stage mirror Z to registers, then overwrite Ts rows 0..7 with X ----
  cplx zmr[8];
  #pragma unroll
  for (int t2 = 0; t2 < 8; ++t2) {
    int m = j + 16*t2;
    int k = col + 256*m;
    int mi = (65536 - k) & 65535;
    zmr[t2] = Ts[g ^ 8][mi >> 8];
  }
  __syncthreads();                     // all Z reads done; Ts rows 0..7 free
  {
    float sn, cs;
    __sincosf(-3.14159265358979324f * (float)(col + 256*j) * (1.0f/65536.0f), &sn, &cs);
    cplx w = cmk(cs, sn);
    const cplx stp = cmk(C16, -S16);
    #pragma unroll
    for (int t2 = 0; t2 < 8; ++t2) {
      int m = j + 16*t2;
      cplx zk = x[t2];
      cplx zm = zmr[t2];
      cplx E = cmk(0.5f*(zk.x + zm.x), 0.5f*(zk.y - zm.y));
      cplx D = cmk(zk.x - zm.x, zk.y + zm.y);
      cplx O = cmk(0.5f*D.y, -0.5f*D.x);
      Xv[c][half][m] = cadd(E, cmul(w, O));
      w = cmul(w, stp);
    }
  }
  if (p == 0 && half == 0 && j == 0) {
    cplx zk = x[8];
    cplx X = cmk(zk.x, -zk.y);
    Xv[c][0][128] = X;
    Xv[c][1][128] = X;
  }
  __syncthreads();

  // ---- Phase M ----
  const int f = g;
  cplx zA[16], zB[16];

// Mirror -> shfl into ZM[15-t2] (used for the LAST pass of a pair and for
// the single-pass columns).
#define MAC_PASS_SHFL(Q, XSEL, ZD, ZM, SRCLANE)                                \
  do {                                                                         \
    const int q_ = (Q);                                                        \
    float sn_, cs_;                                                            \
    __sincosf(3.14159265358979324f * (float)(q_ + 256*j) * (1.0f/65536.0f),    \
              &sn_, &cs_);                                                     \
    cplx wp = cmk(cs_, sn_);                                                   \
    const cplx stp = cmk(C16, S16);                                            \
    const float4* yb = reinterpret_cast<const float4*>(                        \
        Y2 + (((long)q_*16 + f)*129 + j)*8);                                   \
    float4 b0 = yb[0], b1 = yb[1], b2 = yb[2], b3 = yb[3];                     \
    _Pragma("unroll")                                                          \
    for (int t2 = 0; t2 < 8; ++t2) {                                           \
      float4 y0 = b0, y1 = b1, y2 = b2, y3 = b3;                               \
      if (t2 < 7) {                                                            \
        const float4* nx = yb + (long)(t2+1)*64;                               \
        b0 = nx[0]; b1 = nx[1]; b2 = nx[2]; b3 = nx[3];                        \
      }                                                                        \
      int m = j + 16*t2;                                                       \
      cplx S = cmulj(Xv[0][XSEL][m], cmk(y0.x, y0.y));                         \
      S = cadd(S, cmulj(Xv[1][XSEL][m], cmk(y0.z, y0.w)));                     \
      S = cadd(S, cmulj(Xv[2][XSEL][m], cmk(y1.x, y1.y)));                     \
      S = cadd(S, cmulj(Xv[3][XSEL][m], cmk(y1.z, y1.w)));                     \
      S = cadd(S, cmulj(Xv[4][XSEL][m], cmk(y2.x, y2.y)));                     \
      S = cadd(S, cmulj(Xv[5][XSEL][m], cmk(y2.z, y2.w)));                     \
      S = cadd(S, cmulj(Xv[6][XSEL][m], cmk(y3.x, y3.y)));                     \
      S = cadd(S, cmulj(Xv[7][XSEL][m], cmk(y3.z, y3.w)));                     \
      cplx E2 = cmk(0.5f*S.x, 0.5f*S.y);                                       \
      cplx O2 = cmul(wp, E2);                                                  \
      ZD[t2] = cmk(E2.x - O2.y, E2.y + O2.x);                                  \
      float mx = E2.x + O2.y;                                                  \
      float my = O2.x - E2.y;                                                  \
      mx = __shfl(mx, (SRCLANE));                                              \
      my = __shfl(my, (SRCLANE));                                              \
      ZM[15 - t2] = cmk(mx, my);                                               \
      wp = cmul(wp, stp);                                                      \
    }                                                                          \
  } while (0)

// Mirror -> LDS (mir[g*128 + (7-t2)*16 + (j^15)]); read back later as
// zB[8+s] = mir[g*128 + s*16 + j]. Keeps only 8 direct accumulators live.
#define MAC_PASS_LDS(Q, XSEL, ZD)                                              \
  do {                                                                         \
    const int q_ = (Q);                                                        \
    float sn_, cs_;                                                            \
    __sincosf(3.14159265358979324f * (float)(q_ + 256*j) * (1.0f/65536.0f),    \
              &sn_, &cs_);                                                     \
    cplx wp = cmk(cs_, sn_);                                                   \
    const cplx stp = cmk(C16, S16);                                            \
    const float4* yb = reinterpret_cast<const float4*>(                        \
        Y2 + (((long)q_*16 + f)*129 + j)*8);                                   \
    float4 b0 = yb[0], b1 = yb[1], b2 = yb[2], b3 = yb[3];                     \
    _Pragma("unroll")                                                          \
    for (int t2 = 0; t2 < 8; ++t2) {                                           \
      float4 y0 = b0, y1 = b1, y2 = b2, y3 = b3;                               \
      if (t2 < 7) {                                                            \
        const float4* nx = yb + (long)(t2+1)*64;                               \
        b0 = nx[0]; b1 = nx[1]; b2 = nx[2]; b3 = nx[3];                        \
      }                                                                        \
      int m = j + 16*t2;                                                       \
      cplx S = cmulj(Xv[0][XSEL][m], cmk(y0.x, y0.y));                         \
      S = cadd(S, cmulj(Xv[1][XSEL][m], cmk(y0.z, y0.w)));                     \
      S = cadd(S, cmulj(Xv[2][XSEL][m], cmk(y1.x, y1.y)));                     \
      S = cadd(S, cmulj(Xv[3][XSEL][m], cmk(y1.z, y1.w)));                     \
      S = cadd(S, cmulj(Xv[4][XSEL][m], cmk(y2.x, y2.y)));                     \
      S = cadd(S, cmulj(Xv[5][XSEL][m], cmk(y2.z, y2.w)));                     \
      S = cadd(S, cmulj(Xv[6][XSEL][m], cmk(y3.x, y3.y)));                     \
      S = cadd(S, cmulj(Xv[7][XSEL][m], cmk(y3.z, y3.w)));                     \
      cplx E2 = cmk(0.5f*S.x, 0.5f*S.y);                                       \
      cplx O2 = cmul(wp, E2);                                                  \
      ZD[t2] = cmk(E2.x - O2.y, E2.y + O2.x);                                  \
      mir[g*128 + (7 - t2)*16 + (j ^ 15)] = cmk(E2.x + O2.y, O2.x - E2.y);     \
      wp = cmul(wp, stp);                                                      \
    }                                                                          \
  } while (0)

  if (p == 0) {
    // q=0: mirror map is pos 256-m (not 255-m) -> src lane (16-j)&15 and a
    // one-slot shift fixup on lane j==0, plus explicit k=32768 boundary bin.
    int src0 = (t & ~15) | ((16 - j) & 15);
    MAC_PASS_SHFL(0, 0, zA, zA, src0);
    if (j == 0) {
      zA[15] = zA[14]; zA[14] = zA[13]; zA[13] = zA[12]; zA[12] = zA[11];
      zA[11] = zA[10]; zA[10] = zA[9];  zA[9]  = zA[8];
      const float4* yv = reinterpret_cast<const float4*>(
          Y2 + ((long)f*129 + 128)*8);
      float4 y0 = yv[0], y1 = yv[1], y2 = yv[2], y3 = yv[3];
      cplx S = cmulj(Xv[0][1][128], cmk(y0.x, y0.y));
      S = cadd(S, cmulj(Xv[1][1][128], cmk(y0.z, y0.w)));
      S = cadd(S, cmulj(Xv[2][1][128], cmk(y1.x, y1.y)));
      S = cadd(S, cmulj(Xv[3][1][128], cmk(y1.z, y1.w)));
      S = cadd(S, cmulj(Xv[4][1][128], cmk(y2.x, y2.y)));
      S = cadd(S, cmulj(Xv[5][1][128], cmk(y2.z, y2.w)));
      S = cadd(S, cmulj(Xv[6][1][128], cmk(y3.x, y3.y)));
      S = cadd(S, cmulj(Xv[7][1][128], cmk(y3.z, y3.w)));
      zA[8] = cmk(S.x, -S.y);
    }
  } else if (selfp) {            // p == 128
    MAC_PASS_SHFL(128, 0, zA, zA, t ^ 15);
  } else {
    MAC_PASS_LDS(cLo, 0, zA);            // zA direct; zB-uppers -> mir LDS
    MAC_PASS_SHFL(cHi, 1, zB, zA, t ^ 15); // zB direct; zA-uppers via shfl
    #pragma unroll
    for (int s = 0; s < 8; ++s) zB[8 + s] = mir[g*128 + s*16 + j];
  }
#undef MAC_PASS_SHFL
#undef MAC_PASS_LDS

  __syncthreads();               // X/mir reads done; Ts fully reusable below

  // ---- inverse inner DFT-256 over k2 + big twiddle + store ----
#define INV_STORE(Z, MCOL)                                                     \
  do {                                                                         \
    dft16<1>(Z);                                                               \
    {                                                                          \
      float sn_, cs_;                                                          \
      __sincosf(6.28318530717958648f * (float)j * (1.0f/256.0f), &sn_, &cs_);  \
      cplx rr = cmk(cs_, sn_), cur = rr;                                       \
      _Pragma("unroll")                                                        \
      for (int t1 = 1; t1 < 16; ++t1) { Z[t1] = cmul(Z[t1], cur); cur = cmul(cur, rr); } \
    }                                                                          \
    _Pragma("unroll")                                                          \
    for (int t1 = 0; t1 < 16; ++t1) Ts[g][t1*16 + ((j + t1) & 15)] = Z[t1];    \
    _Pragma("unroll")                                                          \
    for (int a2 = 0; a2 < 16; ++a2) Z[a2] = Ts[g][j*16 + ((a2 + j) & 15)];     \
    dft16<1>(Z);                                                               \
    {                                                                          \
      float sn_, cs_;                                                          \
      __sincosf(6.28318530717958648f * (float)((MCOL)*j) * (1.0f/65536.0f), &sn_, &cs_); \
      cplx cur = cmk(cs_, sn_);                                                \
      __sincosf(6.28318530717958648f * (float)(MCOL) * (1.0f/4096.0f), &sn_, &cs_); \
      cplx stp2 = cmk(cs_, sn_);                                               \
      cplx* dst = T2 + (long)(ln*16 + f) * NFFT + (long)(MCOL) * 256;          \
      _Pragma("unroll")                                                        \
      for (int t2 = 0; t2 < 16; ++t2) {                                        \
        dst[j + 16*t2] = cmul(Z[t2], cur);                                     \
        cur = cmul(cur, stp2);                                                 \
      }                                                                        \
    }                                                                          \
  } while (0)

  if (selfp) {
    INV_STORE(zA, cLo);
  } else {
    INV_STORE(zB, cHi);          // zB first: its mirrors came from mir (LDS)
    INV_STORE(zA, cLo);
  }
#undef INV_STORE
}

} // namespace

extern "C" void kernel_launch(void* const* d_in, const int* in_sizes, int n_in,
                              void* d_out, int out_size, void* d_ws, size_t ws_size,
                              hipStream_t stream) {
  const cplx*  x    = (const cplx*)d_in[0];   // (32,8,65536) f32 = 32768 cplx/seq
  const float* wgt  = (const float*)d_in[1];  // (16,8,128)
  const float* bias = (const float*)d_in[2];  // (16,)
  float* out = (float*)d_out;                 // (32,16,65409)

  // Workspace: Y2 (33.8 MB) + T1 (Bn*4 MB) + T2 (Bn*8 MB).
  static const int BnOpt[5] = {16, 8, 4, 2, 1};
  int Bn = 1;
  for (int i = 0; i < 5; ++i) {
    size_t need = Y2BYTES + (size_t)BnOpt[i] * 12582912ull;
    if (need <= ws_size) { Bn = BnOpt[i]; break; }
  }
  char* ws = (char*)d_ws;
  cplx* Y2 = (cplx*)ws;
  cplx* T1 = (cplx*)(ws + Y2BYTES);
  cplx* T2 = (cplx*)(ws + Y2BYTES + (size_t)Bn * 4194304ull);

  weight_spec<<<dim3(256, 8), dim3(256), 0, stream>>>(wgt, Y2);

  for (int n0 = 0; n0 < 32; n0 += Bn) {
    fft_pass_a<-1><<<dim3(Bn*8*16), dim3(256), 0, stream>>>(
        x + (long)n0*8*32768, 32768, 32768, T1);
    if (Bn == 16)
      fused_mid<<<dim3(8, 258), dim3(256), 0, stream>>>(T1, Y2, T2, 1);
    else
      fused_mid<<<dim3(Bn, 129), dim3(256), 0, stream>>>(T1, Y2, T2, 0);
    fft_pass_b<1,1><<<dim3(Bn*16*16), dim3(256), 0, stream>>>(
        T2, (cplx*)nullptr, out, bias, n0*16);
  }
}

// Round 8
// 545.791 us; speedup vs baseline: 2.0534x; 1.0146x over previous
//
#include <hip/hip_runtime.h>

namespace {

constexpr int NFFT  = 65536;   // complex FFT length (half of 131072)
constexpr int OUTW  = 65409;   // W - K + 1
// Y2[k1][f][m][c] : weight rfft spectrum, filter-panel layout for the MAC
constexpr size_t Y2BYTES = (size_t)256 * 16 * 129 * 8 * 8;

typedef float2 cplx;

__device__ __forceinline__ cplx cmk(float x, float y){ return make_float2(x, y); }
__device__ __forceinline__ cplx cadd(cplx a, cplx b){ return cmk(a.x+b.x, a.y+b.y); }
__device__ __forceinline__ cplx csub(cplx a, cplx b){ return cmk(a.x-b.x, a.y-b.y); }
__device__ __forceinline__ cplx cmul(cplx a, cplx b){ return cmk(a.x*b.x - a.y*b.y, a.x*b.y + a.y*b.x); }
__device__ __forceinline__ cplx cmulj(cplx a, cplx b){ // a * conj(b)
  return cmk(a.x*b.x + a.y*b.y, a.y*b.x - a.x*b.y); }

// 16-point complex DFT, natural order in/out. DIR=-1 forward, +1 inverse (unnormalized).
template<int DIR>
__device__ __forceinline__ void dft16(cplx v[16]) {
  const float C1 = 0.92387953251128674f;
  const float S1 = 0.38268343236508977f;
  const float C2 = 0.70710678118654752f;
  const float WR[16]  = {1.f, C1, C2, S1, 0.f, -S1, -C2, -C1, -1.f, -C1, -C2, -S1, 0.f, S1, C2, C1};
  const float WIF[16] = {0.f, -S1, -C2, -C1, -1.f, -C1, -C2, -S1, 0.f, S1, C2, C1, 1.f, C1, C2, S1};
  cplx s[16];
  #pragma unroll
  for (int n2 = 0; n2 < 4; ++n2) {
    cplx a = v[n2], b = v[n2+4], c = v[n2+8], d = v[n2+12];
    cplx ac = cadd(a,c), am = csub(a,c), bd = cadd(b,d), bm = csub(b,d);
    cplx x0 = cadd(ac, bd), x2 = csub(ac, bd), x1, x3;
    if (DIR == -1) { x1 = cmk(am.x + bm.y, am.y - bm.x); x3 = cmk(am.x - bm.y, am.y + bm.x); }
    else           { x1 = cmk(am.x - bm.y, am.y + bm.x); x3 = cmk(am.x + bm.y, am.y - bm.x); }
    s[0*4+n2] = x0;
    {
      int e1 = (n2*1) & 15, e2 = (n2*2) & 15, e3 = (n2*3) & 15;
      cplx w1 = cmk(WR[e1], (DIR==-1)? WIF[e1] : -WIF[e1]);
      cplx w2 = cmk(WR[e2], (DIR==-1)? WIF[e2] : -WIF[e2]);
      cplx w3 = cmk(WR[e3], (DIR==-1)? WIF[e3] : -WIF[e3]);
      s[1*4+n2] = cmul(x1, w1);
      s[2*4+n2] = cmul(x2, w2);
      s[3*4+n2] = cmul(x3, w3);
    }
  }
  #pragma unroll
  for (int t1 = 0; t1 < 4; ++t1) {
    cplx a = s[t1*4+0], b = s[t1*4+1], c = s[t1*4+2], d = s[t1*4+3];
    cplx ac = cadd(a,c), am = csub(a,c), bd = cadd(b,d), bm = csub(b,d);
    cplx x0 = cadd(ac,bd), x2 = csub(ac,bd), x1, x3;
    if (DIR == -1) { x1 = cmk(am.x + bm.y, am.y - bm.x); x3 = cmk(am.x - bm.y, am.y + bm.x); }
    else           { x1 = cmk(am.x - bm.y, am.y + bm.x); x3 = cmk(am.x + bm.y, am.y - bm.x); }
    v[t1+0] = x0; v[t1+4] = x1; v[t1+8] = x2; v[t1+12] = x3;
  }
}

// Four-step pass A (forward): inner 256-pt DFTs + big twiddle.
// k1-major output staged through padded LDS so global stores are contiguous.
template<int DIR>
__global__ __launch_bounds__(256)
void fft_pass_a(const cplx* __restrict__ in, long inStride, int inLen,
                cplx* __restrict__ T) {
  int blk = blockIdx.x;
  int seq = blk >> 4;
  int B0  = (blk & 15) << 4;
  int t = threadIdx.x;
  __shared__ cplx sm[4608];                    // 36864 B: union of two views
  cplx (*tile)[260] = (cplx(*)[260])sm;        // phase-1 view [16][260]
  cplx* tile2 = sm;                            // phase-2 view [256][18]
  {
    const cplx* src = in + (long)seq * inStride;
    int cb = t & 15, rg = t >> 4;
    #pragma unroll
    for (int i = 0; i < 16; ++i) {
      int a = i*16 + rg;
      int sIdx = a*256 + B0 + cb;
      cplx v = (sIdx < inLen) ? src[sIdx] : cmk(0.f, 0.f);
      tile[cb][a] = v;
    }
  }
  __syncthreads();
  int cc = t >> 4, j = t & 15;
  cplx x[16];
  #pragma unroll
  for (int a1 = 0; a1 < 16; ++a1) x[a1] = tile[cc][a1*16 + j];
  dft16<DIR>(x);
  {
    float sn, cs;
    __sincosf((float)DIR * 6.28318530717958648f * (float)j * (1.0f/256.0f), &sn, &cs);
    cplx r = cmk(cs, sn), cur = r;
    #pragma unroll
    for (int t1 = 1; t1 < 16; ++t1) { x[t1] = cmul(x[t1], cur); cur = cmul(cur, r); }
  }
  __syncthreads();
  #pragma unroll
  for (int t1 = 0; t1 < 16; ++t1) tile[cc][t1*16 + ((j + t1) & 15)] = x[t1];
  __syncthreads();
  #pragma unroll
  for (int a2 = 0; a2 < 16; ++a2) x[a2] = tile[cc][j*16 + ((a2 + j) & 15)];
  dft16<DIR>(x);
  int b = B0 + cc;
  __syncthreads();   // tile reads done; reuse as tile2
  {
    float sn, cs;
    __sincosf((float)DIR * 6.28318530717958648f * (float)(b*j) * (1.0f/65536.0f), &sn, &cs);
    cplx cur = cmk(cs, sn);
    __sincosf((float)DIR * 6.28318530717958648f * (float)b * (1.0f/4096.0f), &sn, &cs);
    cplx stp = cmk(cs, sn);
    #pragma unroll
    for (int t2 = 0; t2 < 16; ++t2) {
      tile2[(j + 16*t2)*18 + cc] = cmul(x[t2], cur);
      cur = cmul(cur, stp);
    }
  }
  __syncthreads();
  {
    int rg = t >> 4, cb = t & 15;
    cplx* dst = T + (long)seq * NFFT + B0 + cb;
    #pragma unroll
    for (int i = 0; i < 16; ++i) {
      int k1 = i*16 + rg;
      dst[(long)k1 * 256] = tile2[k1*18 + cb];
    }
  }
}

// Four-step pass B: outer 256-pt DFTs. MODE 1 = inverse-final with bias+trunc.
template<int DIR, int MODE>
__global__ __launch_bounds__(256)
void fft_pass_b(const cplx* __restrict__ T, cplx* __restrict__ outZ,
                float* __restrict__ outR, const float* __restrict__ bias,
                int seqBase) {
  int blk = blockIdx.x;
  int seq = blk >> 4;
  int K0  = (blk & 15) << 4;
  int t = threadIdx.x;
  __shared__ cplx tile[16][260];
  {
    const cplx* src = T + (long)seq * NFFT;
    int ck = t & 15, rg = t >> 4;
    #pragma unroll
    for (int i = 0; i < 16; ++i) {
      int b = i*16 + rg;
      tile[ck][b] = src[b*256 + K0 + ck];
    }
  }
  __syncthreads();
  int cc = t >> 4, j = t & 15;
  cplx x[16];
  #pragma unroll
  for (int a1 = 0; a1 < 16; ++a1) x[a1] = tile[cc][a1*16 + j];
  dft16<DIR>(x);
  {
    float sn, cs;
    __sincosf((float)DIR * 6.28318530717958648f * (float)j * (1.0f/256.0f), &sn, &cs);
    cplx r = cmk(cs, sn), cur = r;
    #pragma unroll
    for (int t1 = 1; t1 < 16; ++t1) { x[t1] = cmul(x[t1], cur); cur = cmul(cur, r); }
  }
  __syncthreads();
  #pragma unroll
  for (int t1 = 0; t1 < 16; ++t1) tile[cc][t1*16 + ((j + t1) & 15)] = x[t1];
  __syncthreads();
  #pragma unroll
  for (int a2 = 0; a2 < 16; ++a2) x[a2] = tile[cc][j*16 + ((a2 + j) & 15)];
  dft16<DIR>(x);
  __syncthreads();
  #pragma unroll
  for (int t2 = 0; t2 < 16; ++t2) tile[cc][j + 16*t2] = x[t2];
  __syncthreads();
  int ck2 = t & 15, rg2 = t >> 4;
  if (MODE == 0) {
    cplx* dst = outZ + (long)seq * NFFT + K0 + ck2;
    #pragma unroll
    for (int i = 0; i < 16; ++i) {
      int k2 = i*16 + rg2;
      dst[256*k2] = tile[ck2][k2];
    }
  } else {
    const float sc = 1.0f / 65536.0f;
    int gseq = seqBase + seq;
    float bf = bias[gseq & 15];
    float* dst = outR + (long)gseq * OUTW;
    #pragma unroll
    for (int i = 0; i < 16; ++i) {
      int k2 = i*16 + rg2;
      int s  = K0 + ck2 + 256*k2;
      int tp = 2*s;
      cplx v = tile[ck2][k2];
      if (tp < OUTW)     dst[tp]   = v.x * sc + bf;
      if (tp + 1 < OUTW) dst[tp+1] = v.y * sc + bf;
    }
  }
}

// Direct weight rfft into panel layout Y2[k1][f][m][c], k = k1 + 256*m.
__global__ __launch_bounds__(256)
void weight_spec(const float* __restrict__ wgt, cplx* __restrict__ Y2) {
  const int k1 = blockIdx.x;      // 0..255
  const int fg = blockIdx.y;      // 0..7
  const int t  = threadIdx.x;
  __shared__ float wt[16][129];
  for (int e = t; e < 16*128; e += 256)
    wt[e >> 7][e & 127] = wgt[(fg*16 + (e >> 7))*128 + (e & 127)];
  __syncthreads();
  const int fcL = t & 15;
  const int fc  = fg*16 + fcL;
  const int f   = fc >> 3;
  const int cch = fc & 7;
  for (int m = t >> 4; m < 129; m += 16) {
    int k = k1 + 256*m;
    if (k > 32768) break;
    float sn, cs;
    __sincosf(-3.14159265358979324f * (float)k * (1.0f/65536.0f), &sn, &cs);
    cplx r  = cmk(cs, sn);
    cplx r2 = cmul(r, r);
    cplx r4 = cmul(r2, r2);
    cplx r8 = cmul(r4, r4);
    cplx av[8];
    #pragma unroll
    for (int v = 0; v < 8; ++v) av[v] = cmk(0.f, 0.f);
    cplx C = cmk(1.f, 0.f);
    #pragma unroll
    for (int u = 0; u < 16; ++u) {
      #pragma unroll
      for (int v = 0; v < 8; ++v) {
        float w = wt[fcL][u*8 + v];
        av[v].x += w * C.x;
        av[v].y += w * C.y;
      }
      C = cmul(C, r8);
    }
    cplx acc = av[7];
    #pragma unroll
    for (int v = 6; v >= 0; --v) acc = cadd(av[v], cmul(r, acc));
    Y2[(((long)k1*16 + f)*129 + m)*8 + cch] = acc;
  }
}

// Fused middle stage v7.
//  - v6 structure (hybrid LDS/shfl mirror path, VGPR=108, LDS 33280 -> 4
//    blocks/CU) PLUS grid-tail fix: the two self-paired columns (0 and 128)
//    merge into ONE block (half 0 = col 0, half 1 = col 128; self-pair
//    mirrors read own group's Z). Grid 2064 -> 2048 = exactly 2 waves of
//    the 1024 resident blocks. v7's 2064 ran a nearly-empty 3rd wave
//    (109 us ~ 3x36; occupancy 18.7% ~ (2 full + 1 empty)/3 of 50% cap).
//    Merging also removes the duplicated forward-DFT the old p=0/128
//    blocks did in both halves. All 2048 blocks now do identical work.
//  - XCD-aware remap kept (round-5: FETCH 164 -> 50 MB).
__global__ __launch_bounds__(256)
void fused_mid(const cplx* __restrict__ T1, const cplx* __restrict__ Y2,
               cplx* __restrict__ T2, int remap) {
  int pe, ln;
  if (remap) {
    int xcd = blockIdx.x;              // 0..7 (= dispatch index % 8)
    int y   = blockIdx.y;              // 0..255
    pe = xcd + 8*(y >> 4);             // 0..127
    ln = y & 15;
  } else {
    ln = blockIdx.x;
    pe = blockIdx.y;                   // 0..127
  }
  const bool merged = (pe == 0);       // handles cols {0, 128}
  const int cLo = pe;                  // merged: 0
  const int cHi = merged ? 128 : (256 - pe);
  const int t = threadIdx.x;
  const int g = t >> 4;                // 16 groups of 16 lanes (wave-aligned)
  const int j = t & 15;
  const int c = g & 7;
  const int half = g >> 3;
  const int col = half ? cHi : cLo;

  __shared__ cplx sm[16*260];          // 33280 B, three views:
  cplx (*Ts)[260]      = (cplx(*)[260])sm;       // transpose / Z-exchange
  cplx (*Xv)[2][130]   = (cplx(*)[2][130])sm;    // X view = Ts rows 0..7
  cplx* mir = &sm[8*260];                        // mirror buf = Ts rows 8..15
                                                 // idx: g*128 + s*16 + j

  const float C16 = 0.98078528040323044913f;  // cos(pi/16)
  const float S16 = 0.19509032201612826785f;  // sin(pi/16)

  // ---- Phase F: forward DFT-256 over b, one column per group-half ----
  cplx x[16];
  {
    const cplx* src = T1 + ((long)(ln*8 + c) * NFFT + (long)col * 256);
    #pragma unroll
    for (int a1 = 0; a1 < 16; ++a1) x[a1] = src[a1*16 + j];
  }
  dft16<-1>(x);
  {
    float sn, cs;
    __sincosf(-6.28318530717958648f * (float)j * (1.0f/256.0f), &sn, &cs);
    cplx r = cmk(cs, sn), cur = r;
    #pragma unroll
    for (int t1 = 1; t1 < 16; ++t1) { x[t1] = cmul(x[t1], cur); cur = cmul(cur, r); }
  }
  #pragma unroll
  for (int t1 = 0; t1 < 16; ++t1) Ts[g][t1*16 + ((j + t1) & 15)] = x[t1];
  #pragma unroll
  for (int a2 = 0; a2 < 16; ++a2) x[a2] = Ts[g][j*16 + ((a2 + j) & 15)];
  dft16<-1>(x);
  #pragma unroll
  for (int t2 = 0; t2 < 16; ++t2) Ts[g][j + 16*t2] = x[t2];
  __syncthreads();

  // ---- stage mirror Z to registers, then overwrite Ts rows 0..7 with X ----
  // Self-paired columns (merged block) mirror within their OWN Z column.
  cplx zmr[8];
  {
    const int gsrc = merged ? g : (g ^ 8);
    #pragma unroll
    for (int t2 = 0; t2 < 8; ++t2) {
      int m = j + 16*t2;
      int k = col + 256*m;
      int mi = (65536 - k) & 65535;
      zmr[t2] = Ts[gsrc][mi >> 8];
    }
  }
  __syncthreads();                     // all Z reads done; Ts rows 0..7 free
  {
    float sn, cs;
    __sincosf(-3.14159265358979324f * (float)(col + 256*j) * (1.0f/65536.0f), &sn, &cs);
    cplx w = cmk(cs, sn);
    const cplx stp = cmk(C16, -S16);
    #pragma unroll
    for (int t2 = 0; t2 < 8; ++t2) {
      int m = j + 16*t2;
      cplx zk = x[t2];
      cplx zm = zmr[t2];
      cplx E = cmk(0.5f*(zk.x + zm.x), 0.5f*(zk.y - zm.y));
      cplx D = cmk(zk.x - zm.x, zk.y + zm.y);
      cplx O = cmk(0.5f*D.y, -0.5f*D.x);
      Xv[c][half][m] = cadd(E, cmul(w, O));
      w = cmul(w, stp);
    }
  }
  if (merged && half == 0 && j == 0) {
    // k = 32768 boundary bin lives at col 0, pos 128: X = conj(Z0[128]).
    cplx zk = x[8];
    Xv[c][0][128] = cmk(zk.x, -zk.y);
  }
  __syncthreads();

  // ---- Phase M ----
  const int f = g;
  cplx zA[16], zB[16];

// Mirror -> shfl into ZM[15-t2] (completes the SECOND column of the pair).
#define MAC_PASS_SHFL(Q, XSEL, ZD, ZM, SRCLANE)                                \
  do {                                                                         \
    const int q_ = (Q);                                                        \
    float sn_, cs_;                                                            \
    __sincosf(3.14159265358979324f * (float)(q_ + 256*j) * (1.0f/65536.0f),    \
              &sn_, &cs_);                                                     \
    cplx wp = cmk(cs_, sn_);                                                   \
    const cplx stp = cmk(C16, S16);                                            \
    const float4* yb = reinterpret_cast<const float4*>(                        \
        Y2 + (((long)q_*16 + f)*129 + j)*8);                                   \
    float4 b0 = yb[0], b1 = yb[1], b2 = yb[2], b3 = yb[3];                     \
    _Pragma("unroll")                                                          \
    for (int t2 = 0; t2 < 8; ++t2) {                                           \
      float4 y0 = b0, y1 = b1, y2 = b2, y3 = b3;                               \
      if (t2 < 7) {                                                            \
        const float4* nx = yb + (long)(t2+1)*64;                               \
        b0 = nx[0]; b1 = nx[1]; b2 = nx[2]; b3 = nx[3];                        \
      }                                                                        \
      int m = j + 16*t2;                                                       \
      cplx S = cmulj(Xv[0][XSEL][m], cmk(y0.x, y0.y));                         \
      S = cadd(S, cmulj(Xv[1][XSEL][m], cmk(y0.z, y0.w)));                     \
      S = cadd(S, cmulj(Xv[2][XSEL][m], cmk(y1.x, y1.y)));                     \
      S = cadd(S, cmulj(Xv[3][XSEL][m], cmk(y1.z, y1.w)));                     \
      S = cadd(S, cmulj(Xv[4][XSEL][m], cmk(y2.x, y2.y)));                     \
      S = cadd(S, cmulj(Xv[5][XSEL][m], cmk(y2.z, y2.w)));                     \
      S = cadd(S, cmulj(Xv[6][XSEL][m], cmk(y3.x, y3.y)));                     \
      S = cadd(S, cmulj(Xv[7][XSEL][m], cmk(y3.z, y3.w)));                     \
      cplx E2 = cmk(0.5f*S.x, 0.5f*S.y);                                       \
      cplx O2 = cmul(wp, E2);                                                  \
      ZD[t2] = cmk(E2.x - O2.y, E2.y + O2.x);                                  \
      float mx = E2.x + O2.y;                                                  \
      float my = O2.x - E2.y;                                                  \
      mx = __shfl(mx, (SRCLANE));                                              \
      my = __shfl(my, (SRCLANE));                                              \
      ZM[15 - t2] = cmk(mx, my);                                               \
      wp = cmul(wp, stp);                                                      \
    }                                                                          \
  } while (0)

// Mirror -> LDS (mir[g*128 + (7-t2)*16 + (j^15)]); read back later as
// zB[8+s] = mir[g*128 + s*16 + j]. Keeps only 8 direct accumulators live.
#define MAC_PASS_LDS(Q, XSEL, ZD)                                              \
  do {                                                                         \
    const int q_ = (Q);                                                        \
    float sn_, cs_;                                                            \
    __sincosf(3.14159265358979324f * (float)(q_ + 256*j) * (1.0f/65536.0f),    \
              &sn_, &cs_);                                                     \
    cplx wp = cmk(cs_, sn_);                                                   \
    const cplx stp = cmk(C16, S16);                                            \
    const float4* yb = reinterpret_cast<const float4*>(                        \
        Y2 + (((long)q_*16 + f)*129 + j)*8);                                   \
    float4 b0 = yb[0], b1 = yb[1], b2 = yb[2], b3 = yb[3];                     \
    _Pragma("unroll")                                                          \
    for (int t2 = 0; t2 < 8; ++t2) {                                           \
      float4 y0 = b0, y1 = b1, y2 = b2, y3 = b3;                               \
      if (t2 < 7) {                                                            \
        const float4* nx = yb + (long)(t2+1)*64;                               \
        b0 = nx[0]; b1 = nx[1]; b2 = nx[2]; b3 = nx[3];                        \
      }                                                                        \
      int m = j + 16*t2;                                                       \
      cplx S = cmulj(Xv[0][XSEL][m], cmk(y0.x, y0.y));                         \
      S = cadd(S, cmulj(Xv[1][XSEL][m], cmk(y0.z, y0.w)));                     \
      S = cadd(S, cmulj(Xv[2][XSEL][m], cmk(y1.x, y1.y)));                     \
      S = cadd(S, cmulj(Xv[3][XSEL][m], cmk(y1.z, y1.w)));                     \
      S = cadd(S, cmulj(Xv[4][XSEL][m], cmk(y2.x, y2.y)));                     \
      S = cadd(S, cmulj(Xv[5][XSEL][m], cmk(y2.z, y2.w)));                     \
      S = cadd(S, cmulj(Xv[6][XSEL][m], cmk(y3.x, y3.y)));                     \
      S = cadd(S, cmulj(Xv[7][XSEL][m], cmk(y3.z, y3.w)));                     \
      cplx E2 = cmk(0.5f*S.x, 0.5f*S.y);                                       \
      cplx O2 = cmul(wp, E2);                                                  \
      ZD[t2] = cmk(E2.x - O2.y, E2.y + O2.x);                                  \
      mir[g*128 + (7 - t2)*16 + (j ^ 15)] = cmk(E2.x + O2.y, O2.x - E2.y);     \
      wp = cmul(wp, stp);                                                      \
    }                                                                          \
  } while (0)

  if (merged) {
    // col 128 (self-paired, standard 255-m mirror map) via LDS macro -> zB;
    // col 0 (mirror map 256-m) via shfl from lane (16-j)&15 + j==0 fixup.
    MAC_PASS_LDS(128, 1, zB);
    int src0 = (t & ~15) | ((16 - j) & 15);
    MAC_PASS_SHFL(0, 0, zA, zA, src0);
    if (j == 0) {
      zA[15] = zA[14]; zA[14] = zA[13]; zA[13] = zA[12]; zA[12] = zA[11];
      zA[11] = zA[10]; zA[10] = zA[9];  zA[9]  = zA[8];
      const float4* yv = reinterpret_cast<const float4*>(
          Y2 + ((long)f*129 + 128)*8);
      float4 y0 = yv[0], y1 = yv[1], y2 = yv[2], y3 = yv[3];
      cplx S = cmulj(Xv[0][0][128], cmk(y0.x, y0.y));
      S = cadd(S, cmulj(Xv[1][0][128], cmk(y0.z, y0.w)));
      S = cadd(S, cmulj(Xv[2][0][128], cmk(y1.x, y1.y)));
      S = cadd(S, cmulj(Xv[3][0][128], cmk(y1.z, y1.w)));
      S = cadd(S, cmulj(Xv[4][0][128], cmk(y2.x, y2.y)));
      S = cadd(S, cmulj(Xv[5][0][128], cmk(y2.z, y2.w)));
      S = cadd(S, cmulj(Xv[6][0][128], cmk(y3.x, y3.y)));
      S = cadd(S, cmulj(Xv[7][0][128], cmk(y3.z, y3.w)));
      zA[8] = cmk(S.x, -S.y);
    }
  } else {
    MAC_PASS_LDS(cLo, 0, zA);              // zA direct; zB-uppers -> mir LDS
    MAC_PASS_SHFL(cHi, 1, zB, zA, t ^ 15); // zB direct; zA-uppers via shfl
  }
  #pragma unroll
  for (int s = 0; s < 8; ++s) zB[8 + s] = mir[g*128 + s*16 + j];
#undef MAC_PASS_SHFL
#undef MAC_PASS_LDS

  __syncthreads();               // X/mir reads done; Ts fully reusable below

  // ---- inverse inner DFT-256 over k2 + big twiddle + store ----
#define INV_STORE(Z, MCOL)                                                     \
  do {                                                                         \
    dft16<1>(Z);                                                               \
    {                                                                          \
      float sn_, cs_;                                                          \
      __sincosf(6.28318530717958648f * (float)j * (1.0f/256.0f), &sn_, &cs_);  \
      cplx rr = cmk(cs_, sn_), cur = rr;                                       \
      _Pragma("unroll")                                                        \
      for (int t1 = 1; t1 < 16; ++t1) { Z[t1] = cmul(Z[t1], cur); cur = cmul(cur, rr); } \
    }                                                                          \
    _Pragma("unroll")                                                          \
    for (int t1 = 0; t1 < 16; ++t1) Ts[g][t1*16 + ((j + t1) & 15)] = Z[t1];    \
    _Pragma("unroll")                                                          \
    for (int a2 = 0; a2 < 16; ++a2) Z[a2] = Ts[g][j*16 + ((a2 + j) & 15)];     \
    dft16<1>(Z);                                                               \
    {                                                                          \
      float sn_, cs_;                                                          \
      __sincosf(6.28318530717958648f * (float)((MCOL)*j) * (1.0f/65536.0f), &sn_, &cs_); \
      cplx cur = cmk(cs_, sn_);                                                \
      __sincosf(6.28318530717958648f * (float)(MCOL) * (1.0f/4096.0f), &sn_, &cs_); \
      cplx stp2 = cmk(cs_, sn_);                                               \
      cplx* dst = T2 + (long)(ln*16 + f) * NFFT + (long)(MCOL) * 256;          \
      _Pragma("unroll")                                                        \
      for (int t2 = 0; t2 < 16; ++t2) {                                        \
        dst[j + 16*t2] = cmul(Z[t2], cur);                                     \
        cur = cmul(cur, stp2);                                                 \
      }                                                                        \
    }                                                                          \
  } while (0)

  INV_STORE(zB, cHi);            // zB first: its mirrors came from mir (LDS)
  INV_STORE(zA, cLo);
#undef INV_STORE
}

} // namespace

extern "C" void kernel_launch(void* const* d_in, const int* in_sizes, int n_in,
                              void* d_out, int out_size, void* d_ws, size_t ws_size,
                              hipStream_t stream) {
  const cplx*  x    = (const cplx*)d_in[0];   // (32,8,65536) f32 = 32768 cplx/seq
  const float* wgt  = (const float*)d_in[1];  // (16,8,128)
  const float* bias = (const float*)d_in[2];  // (16,)
  float* out = (float*)d_out;                 // (32,16,65409)

  // Workspace: Y2 (33.8 MB) + T1 (Bn*4 MB) + T2 (Bn*8 MB).
  static const int BnOpt[5] = {16, 8, 4, 2, 1};
  int Bn = 1;
  for (int i = 0; i < 5; ++i) {
    size_t need = Y2BYTES + (size_t)BnOpt[i] * 12582912ull;
    if (need <= ws_size) { Bn = BnOpt[i]; break; }
  }
  char* ws = (char*)d_ws;
  cplx* Y2 = (cplx*)ws;
  cplx* T1 = (cplx*)(ws + Y2BYTES);
  cplx* T2 = (cplx*)(ws + Y2BYTES + (size_t)Bn * 4194304ull);

  weight_spec<<<dim3(256, 8), dim3(256), 0, stream>>>(wgt, Y2);

  for (int n0 = 0; n0 < 32; n0 += Bn) {
    fft_pass_a<-1><<<dim3(Bn*8*16), dim3(256), 0, stream>>>(
        x + (long)n0*8*32768, 32768, 32768, T1);
    if (Bn == 16)
      fused_mid<<<dim3(8, 256), dim3(256), 0, stream>>>(T1, Y2, T2, 1);
    else
      fused_mid<<<dim3(Bn, 128), dim3(256), 0, stream>>>(T1, Y2, T2, 0);
    fft_pass_b<1,1><<<dim3(Bn*16*16), dim3(256), 0, stream>>>(
        T2, (cplx*)nullptr, out, bias, n0*16);
  }
}